// Round 8
// baseline (677.199 us; speedup 1.0000x reference)
//
#include <hip/hip_runtime.h>
#include <math.h>

typedef _Float16 f16;
typedef _Float16 half8 __attribute__((ext_vector_type(8)));
typedef _Float16 hv2 __attribute__((ext_vector_type(2)));
typedef _Float16 hv4 __attribute__((ext_vector_type(4)));
typedef float f32x4 __attribute__((ext_vector_type(4)));
typedef __attribute__((address_space(1))) const unsigned int gu32;
typedef __attribute__((address_space(3))) unsigned int lu32;

#define BB 32
#define SS 1024
#define DD 512
#define NR (BB*SS)   // 32768
#define CH 16

// ---------- m97-style staging helpers (128B rows, 16B chunks, xor-swizzle row&7) ----------
__device__ __forceinline__ void stage128(const char* g, int ldb, char* lds,
                                         int wv, int ln) {
  #pragma unroll
  for (int r = 0; r < 4; r++) {
    int slot = r * 256 + wv * 64 + ln;
    int row = slot >> 3, cp = slot & 7;
    int c = cp ^ (row & 7);
    const char* gp = g + (size_t)row * ldb + (c << 4);
    char* lp = lds + ((slot - ln) << 4);
    __builtin_amdgcn_global_load_lds((gu32*)gp, (lu32*)lp, 16, 0, 0);
  }
}

// 64 rows x 128B (8KB) staged by 512 threads, one 16B slot each
__device__ __forceinline__ void stage8k_512(const char* g, int ldb, char* lds) {
  int tid = threadIdx.x;
  int slot = tid;
  int row = slot >> 3, cp = slot & 7;
  int c = cp ^ (row & 7);
  const char* gp = g + (size_t)row * ldb + (c << 4);
  char* lp = lds + ((slot - (tid & 63)) << 4);
  __builtin_amdgcn_global_load_lds((gu32*)gp, (lu32*)lp, 16, 0, 0);
}

// 128 rows x 128B (16KB) staged by 512 threads, two 16B slots each
__device__ __forceinline__ void stage16k_512(const char* g, int ldb, char* lds) {
  int tid = threadIdx.x;
  #pragma unroll
  for (int r = 0; r < 2; r++) {
    int slot = r * 512 + tid;
    int row = slot >> 3, cp = slot & 7;
    int c = cp ^ (row & 7);
    const char* gp = g + (size_t)row * ldb + (c << 4);
    char* lp = lds + ((slot - (tid & 63)) << 4);
    __builtin_amdgcn_global_load_lds((gu32*)gp, (lu32*)lp, 16, 0, 0);
  }
}

// k_qk B-stage: 4 slices (q4 = tid>>7) of 32 keys x 128B (4KB each, 16KB total),
// 512 threads x two 16B slots. Per-wave: 2 gload_lds instructions (vmcnt +2).
__device__ __forceinline__ void stageB32(const f16* X, size_t rowbase, int k0,
                                         char* Bset) {
  int tid = threadIdx.x;
  int q4 = tid >> 7;           // wave-uniform (64 consecutive tids share it)
  int inner = tid & 127;
  char* lds = Bset + q4 * 4096;
  const char* g = (const char*)(X + (rowbase + (size_t)q4 * 256) * DD + k0);
  #pragma unroll
  for (int r = 0; r < 2; r++) {
    int slot = r * 128 + inner;
    int row = slot >> 3, cp = slot & 7;
    int c = cp ^ (row & 7);
    const char* gp = g + (size_t)row * 1024 + (c << 4);
    char* lp = lds + ((slot - (tid & 63)) << 4);
    __builtin_amdgcn_global_load_lds((gu32*)gp, (lu32*)lp, 16, 0, 0);
  }
}

__device__ __forceinline__ half8 frag_ld(const char* lds, int row, int kc) {
  return *(const half8*)(lds + row * 128 + ((kc ^ (row & 7)) << 4));
}

__device__ __forceinline__ f32x4 MF(half8 a, half8 b, f32x4 c) {
  return __builtin_amdgcn_mfma_f32_16x16x32_f16(a, b, c, 0, 0, 0);
}

// ---------------- K1: merged embedding+LN; weight split (Wq/Wk plain, Wv transposed) -----
__global__ __launch_bounds__(256) void k_prep(
    const int* __restrict__ inp, const float* __restrict__ wemb,
    const float* __restrict__ pemb, const float* __restrict__ gamma,
    const float* __restrict__ beta, f16* __restrict__ Xhi, f16* __restrict__ Xlo,
    const float* __restrict__ Wq, const float* __restrict__ Wk,
    const float* __restrict__ Wv, f16* __restrict__ Wqh, f16* __restrict__ Wql,
    f16* __restrict__ Wkh, f16* __restrict__ Wkl, f16* __restrict__ Wvt)
{
  int bid = blockIdx.x;
  int tid = threadIdx.x;
  __shared__ float red[10];
  __shared__ float Lt[64][65];
  if (bid >= NR) {
    int t  = bid - NR;           // 0..191
    int mz = t >> 6;             // 0=Wq 1=Wk 2=Wv
    int tt = t & 63;
    if (mz < 2) {                // ---- Wq/Wk: plain hi/lo split, keep [d][h] layout ----
      const float* W = mz ? Wk : Wq;
      f16* Oh = mz ? Wkh : Wqh;
      f16* Ol = mz ? Wkl : Wql;
      #pragma unroll
      for (int p = 0; p < 4; p++) {
        size_t base = (size_t)tt * 4096 + p * 1024 + tid * 4;
        float4 v = *(const float4*)&W[base];
        f16 h0 = (f16)v.x, h1 = (f16)v.y, h2 = (f16)v.z, h3 = (f16)v.w;
        hv4 hi = {h0, h1, h2, h3};
        hv4 lo = {(f16)(v.x - (float)h0), (f16)(v.y - (float)h1),
                  (f16)(v.z - (float)h2), (f16)(v.w - (float)h3)};
        *(hv4*)&Oh[base] = hi;
        *(hv4*)&Ol[base] = lo;
      }
      return;
    }
    // ---- Wv: 64x64 LDS-tiled transpose -> Wvt[h][d] ----
    int tr = tt >> 3, tc = tt & 7;
    int rr = tid >> 4;           // 0..15
    int c4 = (tid & 15) * 4;
    #pragma unroll
    for (int p = 0; p < 4; p++) {
      float4 v = *(const float4*)&Wv[(size_t)(tr * 64 + p * 16 + rr) * DD + tc * 64 + c4];
      Lt[p * 16 + rr][c4 + 0] = v.x; Lt[p * 16 + rr][c4 + 1] = v.y;
      Lt[p * 16 + rr][c4 + 2] = v.z; Lt[p * 16 + rr][c4 + 3] = v.w;
    }
    __syncthreads();
    #pragma unroll
    for (int p = 0; p < 4; p++) {
      int dl = p * 16 + rr;
      float v0 = Lt[c4 + 0][dl], v1 = Lt[c4 + 1][dl];
      float v2 = Lt[c4 + 2][dl], v3 = Lt[c4 + 3][dl];
      size_t o = (size_t)(tc * 64 + dl) * DD + tr * 64 + c4;
      *(hv4*)&Wvt[o] = (hv4){(f16)v0, (f16)v1, (f16)v2, (f16)v3};
    }
    return;
  }
  // ---- embedding + layernorm -> split fp16 X ----
  int row = bid;
  int s   = row & (SS - 1);
  int tok = inp[row];
  float2 w = ((const float2*)(wemb + (size_t)tok * DD))[tid];
  float2 p = ((const float2*)(pemb + (size_t)s   * DD))[tid];
  float ex = w.x + p.x, ey = w.y + p.y;
  float sum = ex + ey, ssq = ex*ex + ey*ey;
  #pragma unroll
  for (int off = 32; off > 0; off >>= 1) {
    sum += __shfl_down(sum, off, 64);
    ssq += __shfl_down(ssq, off, 64);
  }
  int wv = tid >> 6, ln = tid & 63;
  if (ln == 0) { red[wv] = sum; red[4 + wv] = ssq; }
  __syncthreads();
  if (tid == 0) {
    float s4 = red[0] + red[1] + red[2] + red[3];
    float q4 = red[4] + red[5] + red[6] + red[7];
    float mean = s4 * (1.0f / DD);
    float var  = q4 * (1.0f / DD) - mean * mean;
    red[8] = mean; red[9] = rsqrtf(var + 1e-5f);
  }
  __syncthreads();
  float mean = red[8], rstd = red[9];
  float2 g  = ((const float2*)gamma)[tid];
  float2 bt = ((const float2*)beta)[tid];
  float ox = (ex - mean) * rstd * g.x + bt.x;
  float oy = (ey - mean) * rstd * g.y + bt.y;
  f16 hx = (f16)ox, hy = (f16)oy;
  f16 lx = (f16)(ox - (float)hx), ly = (f16)(oy - (float)hy);
  ((hv2*)(Xhi + (size_t)row * DD))[tid] = (hv2){hx, hy};
  ((hv2*)(Xlo + (size_t)row * DD))[tid] = (hv2){lx, ly};
}

// ---------------- K2a: Mt[e][d] = sum_h Wk[e][h] Wq[d][h] (3-term split) -----
__global__ __launch_bounds__(256, 2) void k_mt(
    const f16* __restrict__ Wkh, const f16* __restrict__ Wkl,
    const f16* __restrict__ Wqh, const f16* __restrict__ Wql,
    f16* __restrict__ Mthi, f16* __restrict__ Mtlo)
{
  __shared__ __align__(16) char Ah[16384], Al[16384], Bh[16384], Bl[16384];
  int tid = threadIdx.x, wv = tid >> 6, ln = tid & 63;
  int mw = wv & 1, nw = wv >> 1;
  int n0 = blockIdx.x * 128;   // d
  int m0 = blockIdx.y * 128;   // e
  f32x4 acc[4][4];
  #pragma unroll
  for (int i = 0; i < 4; i++)
    #pragma unroll
    for (int j = 0; j < 4; j++) acc[i][j] = (f32x4)(0.0f);
  int quad = ln >> 4, l15 = ln & 15;
  for (int k0 = 0; k0 < DD; k0 += 64) {
    __syncthreads();
    stage128((const char*)(Wkh + (size_t)m0 * DD + k0), 1024, Ah, wv, ln);
    stage128((const char*)(Wkl + (size_t)m0 * DD + k0), 1024, Al, wv, ln);
    stage128((const char*)(Wqh + (size_t)n0 * DD + k0), 1024, Bh, wv, ln);
    stage128((const char*)(Wql + (size_t)n0 * DD + k0), 1024, Bl, wv, ln);
    __syncthreads();
    #pragma unroll
    for (int ks = 0; ks < 2; ks++) {
      int kc = ks * 4 + quad;
      half8 ah[4], al[4], bh[4], bl[4];
      #pragma unroll
      for (int t = 0; t < 4; t++) {
        ah[t] = frag_ld(Ah, mw * 64 + t * 16 + l15, kc);
        al[t] = frag_ld(Al, mw * 64 + t * 16 + l15, kc);
        bh[t] = frag_ld(Bh, nw * 64 + t * 16 + l15, kc);
        bl[t] = frag_ld(Bl, nw * 64 + t * 16 + l15, kc);
      }
      #pragma unroll
      for (int i = 0; i < 4; i++)
        #pragma unroll
        for (int j = 0; j < 4; j++) {
          acc[i][j] = MF(ah[i], bh[j], acc[i][j]);
          acc[i][j] = MF(ah[i], bl[j], acc[i][j]);
          acc[i][j] = MF(al[i], bh[j], acc[i][j]);
        }
    }
  }
  #pragma unroll
  for (int i = 0; i < 4; i++)
    #pragma unroll
    for (int j = 0; j < 4; j++)
      #pragma unroll
      for (int rg = 0; rg < 4; rg++) {
        int gm = m0 + mw * 64 + i * 16 + quad * 4 + rg;   // e
        int gn = n0 + nw * 64 + j * 16 + l15;             // d
        size_t o = (size_t)gm * DD + gn;
        float v = acc[i][j][rg];
        f16 h = (f16)v;
        Mthi[o] = h; Mtlo[o] = (f16)(v - (float)h);
      }
}

// ---------------- K2b: Sq = X * Mt^T (split x split, 3-term) ----------------
// 8 waves, 128x128 tile: 64KB LDS + <=128 reg/wave -> 2 blocks/CU (4 waves/SIMD).
__global__ __launch_bounds__(512, 4) void k_projm(
    const f16* __restrict__ Xhi, const f16* __restrict__ Xlo,
    const f16* __restrict__ Mthi, const f16* __restrict__ Mtlo,
    f16* __restrict__ Sqhi, f16* __restrict__ Sqlo)
{
  __shared__ __align__(16) char Ah[16384], Al[16384], Bh[16384], Bl[16384];
  int tid = threadIdx.x, wv = tid >> 6, ln = tid & 63;
  int mw = wv & 1, nw = wv >> 1;       // nw in [0,4): 32-col slice
  // swizzle: L = (y&7) + 8x + 32*(y>>3); the 4 same-m0 blocks share an XCD
  int L = blockIdx.x;
  int xb = (L >> 3) & 3;
  int y  = ((L >> 5) << 3) + (L & 7);
  int n0 = xb * 128;  // e
  int m0 = y * 128;   // s
  f32x4 acc[4][2];
  #pragma unroll
  for (int i = 0; i < 4; i++)
    #pragma unroll
    for (int j = 0; j < 2; j++) acc[i][j] = (f32x4)(0.0f);
  int quad = ln >> 4, l15 = ln & 15;
  for (int k0 = 0; k0 < DD; k0 += 64) {
    __syncthreads();
    stage16k_512((const char*)(Xhi  + (size_t)m0 * DD + k0), 1024, Ah);
    stage16k_512((const char*)(Xlo  + (size_t)m0 * DD + k0), 1024, Al);
    stage16k_512((const char*)(Mthi + (size_t)n0 * DD + k0), 1024, Bh);
    stage16k_512((const char*)(Mtlo + (size_t)n0 * DD + k0), 1024, Bl);
    __syncthreads();
    #pragma unroll
    for (int ks = 0; ks < 2; ks++) {
      int kc = ks * 4 + quad;
      half8 ah[4], al[4], bh[2], bl[2];
      #pragma unroll
      for (int t = 0; t < 4; t++) {
        ah[t] = frag_ld(Ah, mw * 64 + t * 16 + l15, kc);
        al[t] = frag_ld(Al, mw * 64 + t * 16 + l15, kc);
      }
      #pragma unroll
      for (int t = 0; t < 2; t++) {
        bh[t] = frag_ld(Bh, nw * 32 + t * 16 + l15, kc);
        bl[t] = frag_ld(Bl, nw * 32 + t * 16 + l15, kc);
      }
      #pragma unroll
      for (int i = 0; i < 4; i++)
        #pragma unroll
        for (int j = 0; j < 2; j++) {
          acc[i][j] = MF(ah[i], bh[j], acc[i][j]);
          acc[i][j] = MF(ah[i], bl[j], acc[i][j]);
          acc[i][j] = MF(al[i], bh[j], acc[i][j]);
        }
    }
  }
  #pragma unroll
  for (int i = 0; i < 4; i++)
    #pragma unroll
    for (int j = 0; j < 2; j++)
      #pragma unroll
      for (int rg = 0; rg < 4; rg++) {
        int gm = m0 + mw * 64 + i * 16 + quad * 4 + rg;
        int gn = n0 + nw * 32 + j * 16 + l15;
        size_t o = (size_t)gm * DD + gn;
        float v = acc[i][j][rg];
        f16 h = (f16)v;
        Sqhi[o] = h; Sqlo[o] = (f16)(v - (float)h);
      }
}

// ---------------- K3: Vt GEMM (plain fp16): Vt[d][s], ping-pong pipelined ----------
__global__ __launch_bounds__(256, 2) void k_vt(
    const f16* __restrict__ Wvt, const f16* __restrict__ Xhi, f16* __restrict__ Vt)
{
  __shared__ __align__(16) char Ah[2][16384], Bh[2][16384];
  int tid = threadIdx.x, wv = tid >> 6, ln = tid & 63;
  int mw = wv & 1, nw = wv >> 1;
  // XCD-bijective swizzle (nwg=1024): XCD c owns s-tiles [c*32,(c+1)*32), all 4 d-tiles
  int orig = blockIdx.x;
  int L = (orig & 7) * 128 + (orig >> 3);
  int c = L >> 7, t = L & 127;
  int m0 = (t & 3) * 128;                // d
  int n0 = (c * 32 + (t >> 2)) * 128;    // s
  f32x4 acc[4][4];
  #pragma unroll
  for (int i = 0; i < 4; i++)
    #pragma unroll
    for (int j = 0; j < 4; j++) acc[i][j] = (f32x4)(0.0f);
  int quad = ln >> 4, l15 = ln & 15;
  // prologue
  stage128((const char*)(Wvt + (size_t)m0 * DD), 1024, Ah[0], wv, ln);
  stage128((const char*)(Xhi + (size_t)n0 * DD), 1024, Bh[0], wv, ln);
  for (int k0 = 0; k0 < DD; k0 += 64) {
    int cur = (k0 >> 6) & 1;
    __builtin_amdgcn_s_barrier();
    __builtin_amdgcn_sched_barrier(0);
    if (k0 + 64 < DD) {
      stage128((const char*)(Wvt + (size_t)m0 * DD + k0 + 64), 1024, Ah[cur ^ 1], wv, ln);
      stage128((const char*)(Xhi + (size_t)n0 * DD + k0 + 64), 1024, Bh[cur ^ 1], wv, ln);
      asm volatile("s_waitcnt vmcnt(8)" ::: "memory");
    } else {
      asm volatile("s_waitcnt vmcnt(0)" ::: "memory");
    }
    __builtin_amdgcn_s_barrier();
    __builtin_amdgcn_sched_barrier(0);
    #pragma unroll
    for (int ks = 0; ks < 2; ks++) {
      int kc = ks * 4 + quad;
      half8 a[4], b[4];
      #pragma unroll
      for (int tt = 0; tt < 4; tt++) {
        a[tt] = frag_ld(Ah[cur], mw * 64 + tt * 16 + l15, kc);
        b[tt] = frag_ld(Bh[cur], nw * 64 + tt * 16 + l15, kc);
      }
      #pragma unroll
      for (int i = 0; i < 4; i++)
        #pragma unroll
        for (int j = 0; j < 4; j++) acc[i][j] = MF(a[i], b[j], acc[i][j]);
    }
  }
  #pragma unroll
  for (int i = 0; i < 4; i++)
    #pragma unroll
    for (int j = 0; j < 4; j++)
      #pragma unroll
      for (int rg = 0; rg < 4; rg++) {
        int gm = m0 + mw * 64 + i * 16 + quad * 4 + rg;   // d
        int gn = n0 + nw * 64 + j * 16 + l15;             // s
        Vt[(size_t)gm * NR + gn] = (f16)acc[i][j][rg];
      }
}

// ---------------- K4: fused S = Sq X^T / sqrt(D) + row softmax -> P fp16 -------------
// 512 threads, block = 64 q x 1024 k x 1 batch. 80 KB LDS -> 2 blocks/CU.
// 8 sub-phases per k0 (32-key B slices), B ping-pong + counted vmcnt(4)/(6);
// A staged to LDS, prefetched one k0 ahead at r==7, hoisted to regs at r==0.
// Softmax red arrays aliased over the dead B buffer in the epilogue.
__global__ __launch_bounds__(512, 4) void k_qk(
    const f16* __restrict__ Sqhi, const f16* __restrict__ Sqlo,
    const f16* __restrict__ Xhi, const f16* __restrict__ Xlo,
    f16* __restrict__ Pws, f16* __restrict__ Pd)
{
  __shared__ __align__(16) char Ah[8192], Al[8192];
  __shared__ __align__(16) char Bh[2][16384], Bl[2][16384];   // [buf][q4*4096 + ...]
  int tid = threadIdx.x, wv = tid >> 6, ln = tid & 63;
  int rowg = wv & 1, qd = wv >> 1;
  // swizzle decode: L = g*128 + j*8 + xcd;  z = g*8 + xcd, m0 = j*64
  int L = blockIdx.x;
  int g  = L >> 7;
  int rr = L & 127;
  int z  = g * 8 + (rr & 7);
  int m0 = (rr >> 3) * 64;
  size_t zr = (size_t)z * SS;
  f32x4 acc[2][16];
  #pragma unroll
  for (int i = 0; i < 2; i++)
    #pragma unroll
    for (int j = 0; j < 16; j++) acc[i][j] = (f32x4)(0.0f);
  int quad = ln >> 4, l15 = ln & 15;

  // prologue: A(k0=0) then B(k0=0, r=0) into buf 0 -> in flight: A2 + B4
  stage8k_512((const char*)(Sqhi + (zr + m0) * DD), 1024, Ah);
  stage8k_512((const char*)(Sqlo + (zr + m0) * DD), 1024, Al);
  stageB32(Xhi, zr + 0, 0, Bh[0]);
  stageB32(Xlo, zr + 0, 0, Bl[0]);

  half8 afh[2][2], afl[2][2];   // A-fragments for the current k0, reused across r
  for (int k0 = 0; k0 < DD; k0 += 64) {
    #pragma unroll
    for (int r = 0; r < 8; r++) {
      // barrier1: all waves done reading buf[(r+1)&1] (from phase p-1) before overwrite
      __builtin_amdgcn_s_barrier();
      __builtin_amdgcn_sched_barrier(0);
      bool lastPhase = (k0 == DD - 64 && r == 7);
      if (!lastPhase) {
        int nk0 = (r == 7) ? k0 + 64 : k0;
        int nr  = (r + 1) & 7;
        stageB32(Xhi, zr + nr * 32, nk0, Bh[(r + 1) & 1]);
        stageB32(Xlo, zr + nr * 32, nk0, Bl[(r + 1) & 1]);
        if (r == 7) {
          // prefetch A for next k0 (single buffer: only reader is next r==0 hoist)
          stage8k_512((const char*)(Sqhi + (zr + m0) * DD + k0 + 64), 1024, Ah);
          stage8k_512((const char*)(Sqlo + (zr + m0) * DD + k0 + 64), 1024, Al);
          asm volatile("s_waitcnt vmcnt(6)" ::: "memory");
        } else {
          asm volatile("s_waitcnt vmcnt(4)" ::: "memory");
        }
      } else {
        asm volatile("s_waitcnt vmcnt(0)" ::: "memory");
      }
      __builtin_amdgcn_s_barrier();
      __builtin_amdgcn_sched_barrier(0);
      if (r == 0) {   // hoist A-fragments: 8 ds_reads per k0
        #pragma unroll
        for (int ks = 0; ks < 2; ks++)
          #pragma unroll
          for (int i = 0; i < 2; i++) {
            afh[ks][i] = frag_ld(Ah, rowg * 32 + i * 16 + l15, ks * 4 + quad);
            afl[ks][i] = frag_ld(Al, rowg * 32 + i * 16 + l15, ks * 4 + quad);
          }
      }
      const char* Bhc = Bh[r & 1] + qd * 4096;
      const char* Blc = Bl[r & 1] + qd * 4096;
      #pragma unroll
      for (int ks = 0; ks < 2; ks++) {
        int kc = ks * 4 + quad;
        #pragma unroll
        for (int jj = 0; jj < 2; jj++) {
          half8 bh = frag_ld(Bhc, jj * 16 + l15, kc);
          half8 bl = frag_ld(Blc, jj * 16 + l15, kc);
          #pragma unroll
          for (int i = 0; i < 2; i++) {
            acc[i][r * 2 + jj] = MF(afh[ks][i], bh, acc[i][r * 2 + jj]);
            acc[i][r * 2 + jj] = MF(afh[ks][i], bl, acc[i][r * 2 + jj]);
            acc[i][r * 2 + jj] = MF(afl[ks][i], bh, acc[i][r * 2 + jj]);
          }
        }
      }
    }
  }
  __syncthreads();   // all MFMA done -> B buffers free for red alias
  float* redm = (float*)&Bh[0][0];     // [4][64] -> qd*64 + row
  float* reds = redm + 256;

  // ---- fused softmax over the full 1024-key row ----
  const float scale = 0.044194173824159216f;   // 1/sqrt(512)
  float mx[2][4];
  #pragma unroll
  for (int i = 0; i < 2; i++)
    #pragma unroll
    for (int rg = 0; rg < 4; rg++) mx[i][rg] = -3.0e38f;
  #pragma unroll
  for (int i = 0; i < 2; i++)
    #pragma unroll
    for (int j = 0; j < 16; j++)
      #pragma unroll
      for (int rg = 0; rg < 4; rg++) {
        acc[i][j][rg] *= scale;
        mx[i][rg] = fmaxf(mx[i][rg], acc[i][j][rg]);
      }
  #pragma unroll
  for (int off = 1; off < 16; off <<= 1)
    #pragma unroll
    for (int i = 0; i < 2; i++)
      #pragma unroll
      for (int rg = 0; rg < 4; rg++)
        mx[i][rg] = fmaxf(mx[i][rg], __shfl_xor(mx[i][rg], off, 64));
  if (l15 == 0) {
    #pragma unroll
    for (int i = 0; i < 2; i++)
      #pragma unroll
      for (int rg = 0; rg < 4; rg++)
        redm[qd * 64 + rowg * 32 + i * 16 + quad * 4 + rg] = mx[i][rg];
  }
  __syncthreads();
  float fm[2][4], sum[2][4];
  #pragma unroll
  for (int i = 0; i < 2; i++)
    #pragma unroll
    for (int rg = 0; rg < 4; rg++) {
      int row = rowg * 32 + i * 16 + quad * 4 + rg;
      fm[i][rg] = fmaxf(fmaxf(redm[row], redm[64 + row]),
                        fmaxf(redm[128 + row], redm[192 + row]));
      sum[i][rg] = 0.0f;
    }
  #pragma unroll
  for (int i = 0; i < 2; i++)
    #pragma unroll
    for (int j = 0; j < 16; j++)
      #pragma unroll
      for (int rg = 0; rg < 4; rg++) {
        float e = __expf(acc[i][j][rg] - fm[i][rg]);
        acc[i][j][rg] = e;
        sum[i][rg] += e;
      }
  #pragma unroll
  for (int off = 1; off < 16; off <<= 1)
    #pragma unroll
    for (int i = 0; i < 2; i++)
      #pragma unroll
      for (int rg = 0; rg < 4; rg++)
        sum[i][rg] += __shfl_xor(sum[i][rg], off, 64);
  if (l15 == 0) {
    #pragma unroll
    for (int i = 0; i < 2; i++)
      #pragma unroll
      for (int rg = 0; rg < 4; rg++)
        reds[qd * 64 + rowg * 32 + i * 16 + quad * 4 + rg] = sum[i][rg];
  }
  __syncthreads();
  float inv[2][4];
  #pragma unroll
  for (int i = 0; i < 2; i++)
    #pragma unroll
    for (int rg = 0; rg < 4; rg++) {
      int row = rowg * 32 + i * 16 + quad * 4 + rg;
      inv[i][rg] = 1.0f / (reds[row] + reds[64 + row] + reds[128 + row] + reds[192 + row]);
    }
  f16* Pb = (z < CH) ? Pws : Pd;
  size_t zo = (size_t)((z < CH) ? z : z - CH);
  #pragma unroll
  for (int i = 0; i < 2; i++)
    #pragma unroll
    for (int j = 0; j < 16; j++)
      #pragma unroll
      for (int rg = 0; rg < 4; rg++) {
        int row = rowg * 32 + i * 16 + quad * 4 + rg;
        int col = qd * 256 + j * 16 + l15;
        Pb[(zo * SS + m0 + row) * SS + col] = (f16)(acc[i][j][rg] * inv[i][rg]);
      }
}

// ---------------- K6: O = P V  (fp16 MFMA), ping-pong pipelined, XCD swizzle --------
__global__ __launch_bounds__(256, 2) void k_pv(
    const f16* __restrict__ P, const f16* __restrict__ Vt, float* __restrict__ O,
    int zoff)
{
  __shared__ __align__(16) char Ah[2][16384], Bh[2][16384];
  int tid = threadIdx.x, wv = tid >> 6, ln = tid & 63;
  int mw = wv & 1, nw = wv >> 1;
  // XCD-bijective swizzle (nwg=512): XCD c owns batches {2c, 2c+1}
  int orig = blockIdx.x;
  int L = (orig & 7) * 64 + (orig >> 3);
  int c = L >> 6, t = L & 63;
  int zl = 2 * c + (t >> 5);          // 0..15
  int m0 = ((t >> 2) & 7) * 128;      // query (within batch)
  int n0 = (t & 3) * 128;             // d_out
  int b  = zoff + zl;                 // global batch
  const char* Pt = (const char*)(P + ((size_t)zl * SS + m0) * SS);
  const char* Vb = (const char*)(Vt + (size_t)n0 * NR + (size_t)b * SS);
  f32x4 acc[4][4];
  #pragma unroll
  for (int i = 0; i < 4; i++)
    #pragma unroll
    for (int j = 0; j < 4; j++) acc[i][j] = (f32x4)(0.0f);
  int quad = ln >> 4, l15 = ln & 15;
  // prologue
  stage128(Pt, 2048, Ah[0], wv, ln);
  stage128(Vb, NR * 2, Bh[0], wv, ln);
  for (int k0 = 0; k0 < SS; k0 += 64) {
    int cur = (k0 >> 6) & 1;
    __builtin_amdgcn_s_barrier();
    __builtin_amdgcn_sched_barrier(0);
    if (k0 + 64 < SS) {
      stage128(Pt + (k0 + 64) * 2, 2048, Ah[cur ^ 1], wv, ln);
      stage128(Vb + (k0 + 64) * 2, NR * 2, Bh[cur ^ 1], wv, ln);
      asm volatile("s_waitcnt vmcnt(8)" ::: "memory");
    } else {
      asm volatile("s_waitcnt vmcnt(0)" ::: "memory");
    }
    __builtin_amdgcn_s_barrier();
    __builtin_amdgcn_sched_barrier(0);
    #pragma unroll
    for (int ks = 0; ks < 2; ks++) {
      int kc = ks * 4 + quad;
      half8 a[4], bf[4];
      #pragma unroll
      for (int tt = 0; tt < 4; tt++) {
        a[tt]  = frag_ld(Ah[cur], mw * 64 + tt * 16 + l15, kc);
        bf[tt] = frag_ld(Bh[cur], nw * 64 + tt * 16 + l15, kc);
      }
      #pragma unroll
      for (int i = 0; i < 4; i++)
        #pragma unroll
        for (int j = 0; j < 4; j++) acc[i][j] = MF(a[i], bf[j], acc[i][j]);
    }
  }
  #pragma unroll
  for (int i = 0; i < 4; i++)
    #pragma unroll
    for (int j = 0; j < 4; j++)
      #pragma unroll
      for (int rg = 0; rg < 4; rg++) {
        int gm = m0 + mw * 64 + i * 16 + quad * 4 + rg;
        int gn = n0 + nw * 64 + j * 16 + l15;
        O[((size_t)b * SS + gm) * DD + gn] = acc[i][j][rg];
      }
}

extern "C" void kernel_launch(void* const* d_in, const int* in_sizes, int n_in,
                              void* d_out, int out_size, void* d_ws, size_t ws_size,
                              hipStream_t stream) {
  const int*   inp   = (const int*)d_in[0];
  const float* wemb  = (const float*)d_in[1];
  const float* pemb  = (const float*)d_in[2];
  const float* gamma = (const float*)d_in[3];
  const float* beta  = (const float*)d_in[4];
  const float* Wk    = (const float*)d_in[5];
  const float* Wq    = (const float*)d_in[6];
  const float* Wv    = (const float*)d_in[7];

  // ws (192 MiB): [Xhi 32M][Xlo 32M][Sqhi 32M][Sqlo 32M][Vt 32M][Pws 32M]
  // P batches 0..15 -> Pws; batches 16..31 -> d_out[0,32M).
  // k_pv runs b=16..31 first (reads d_out[0,32M), writes d_out[32,64M)),
  // then b=0..15 (reads Pws, writes d_out[0,32M)). Stream order makes this safe.
  char* ws = (char*)d_ws;
  f16* Xhi  = (f16*)ws;
  f16* Xlo  = (f16*)(ws + ((size_t)32 << 20));
  f16* Sqhi = (f16*)(ws + ((size_t)64 << 20));
  f16* Sqlo = (f16*)(ws + ((size_t)96 << 20));
  f16* Vt   = (f16*)(ws + ((size_t)128 << 20));
  f16* Pws  = (f16*)(ws + ((size_t)160 << 20));
  f16* Pd   = (f16*)d_out;

  f16* Wqh  = (f16*)d_out;
  f16* Wql  = Wqh + (size_t)DD * DD;
  f16* Wkh  = Wql + (size_t)DD * DD;
  f16* Wkl  = Wkh + (size_t)DD * DD;
  f16* Wvt  = Wkl + (size_t)DD * DD;
  f16* Mthi = Wvt + (size_t)DD * DD;
  f16* Mtlo = Mthi + (size_t)DD * DD;

  k_prep<<<NR + 192, 256, 0, stream>>>(inp, wemb, pemb, gamma, beta, Xhi, Xlo,
                                       Wq, Wk, Wv, Wqh, Wql, Wkh, Wkl, Wvt);
  k_mt<<<dim3(DD / 128, DD / 128), 256, 0, stream>>>(Wkh, Wkl, Wqh, Wql, Mthi, Mtlo);
  k_projm<<<1024, 512, 0, stream>>>(Xhi, Xlo, Mthi, Mtlo, Sqhi, Sqlo);
  k_vt<<<1024, 256, 0, stream>>>(Wvt, Xhi, Vt);
  k_qk<<<512, 512, 0, stream>>>(Sqhi, Sqlo, Xhi, Xlo, Pws, Pd);
  k_pv<<<512, 256, 0, stream>>>(Pd,  Vt, (float*)d_out, CH);
  k_pv<<<512, 256, 0, stream>>>(Pws, Vt, (float*)d_out, 0);
}

// Round 9
// 425.779 us; speedup vs baseline: 1.5905x; 1.5905x over previous
//
#include <hip/hip_runtime.h>
#include <math.h>

typedef _Float16 f16;
typedef _Float16 half8 __attribute__((ext_vector_type(8)));
typedef _Float16 hv2 __attribute__((ext_vector_type(2)));
typedef _Float16 hv4 __attribute__((ext_vector_type(4)));
typedef float f32x4 __attribute__((ext_vector_type(4)));
typedef __attribute__((address_space(1))) const unsigned int gu32;
typedef __attribute__((address_space(3))) unsigned int lu32;

#define BB 32
#define SS 1024
#define DD 512
#define NR (BB*SS)   // 32768
#define CH 16

// ---------- m97-style staging helpers (128B rows, 16B chunks, xor-swizzle row&7) ----------
__device__ __forceinline__ void stage128(const char* g, int ldb, char* lds,
                                         int wv, int ln) {
  #pragma unroll
  for (int r = 0; r < 4; r++) {
    int slot = r * 256 + wv * 64 + ln;
    int row = slot >> 3, cp = slot & 7;
    int c = cp ^ (row & 7);
    const char* gp = g + (size_t)row * ldb + (c << 4);
    char* lp = lds + ((slot - ln) << 4);
    __builtin_amdgcn_global_load_lds((gu32*)gp, (lu32*)lp, 16, 0, 0);
  }
}

// 64 rows x 128B (8KB) staged by 512 threads, one 16B slot each
__device__ __forceinline__ void stage8k_512(const char* g, int ldb, char* lds) {
  int tid = threadIdx.x;
  int slot = tid;
  int row = slot >> 3, cp = slot & 7;
  int c = cp ^ (row & 7);
  const char* gp = g + (size_t)row * ldb + (c << 4);
  char* lp = lds + ((slot - (tid & 63)) << 4);
  __builtin_amdgcn_global_load_lds((gu32*)gp, (lu32*)lp, 16, 0, 0);
}

// 128 rows x 128B (16KB) staged by 512 threads, two 16B slots each
__device__ __forceinline__ void stage16k_512(const char* g, int ldb, char* lds) {
  int tid = threadIdx.x;
  #pragma unroll
  for (int r = 0; r < 2; r++) {
    int slot = r * 512 + tid;
    int row = slot >> 3, cp = slot & 7;
    int c = cp ^ (row & 7);
    const char* gp = g + (size_t)row * ldb + (c << 4);
    char* lp = lds + ((slot - (tid & 63)) << 4);
    __builtin_amdgcn_global_load_lds((gu32*)gp, (lu32*)lp, 16, 0, 0);
  }
}

// k_qk B-stage: 4 slices (q4 = tid>>7) of 32 keys x 128B (4KB each, 16KB total),
// 512 threads x two 16B slots. Per-wave: 2 gload_lds instructions (vmcnt +2).
__device__ __forceinline__ void stageB32(const f16* X, size_t rowbase, int k0,
                                         char* Bset) {
  int tid = threadIdx.x;
  int q4 = tid >> 7;           // wave-uniform (64 consecutive tids share it)
  int inner = tid & 127;
  char* lds = Bset + q4 * 4096;
  const char* g = (const char*)(X + (rowbase + (size_t)q4 * 256) * DD + k0);
  #pragma unroll
  for (int r = 0; r < 2; r++) {
    int slot = r * 128 + inner;
    int row = slot >> 3, cp = slot & 7;
    int c = cp ^ (row & 7);
    const char* gp = g + (size_t)row * 1024 + (c << 4);
    char* lp = lds + ((slot - (tid & 63)) << 4);
    __builtin_amdgcn_global_load_lds((gu32*)gp, (lu32*)lp, 16, 0, 0);
  }
}

__device__ __forceinline__ half8 frag_ld(const char* lds, int row, int kc) {
  return *(const half8*)(lds + row * 128 + ((kc ^ (row & 7)) << 4));
}

__device__ __forceinline__ f32x4 MF(half8 a, half8 b, f32x4 c) {
  return __builtin_amdgcn_mfma_f32_16x16x32_f16(a, b, c, 0, 0, 0);
}

// ---------------- K1: merged embedding+LN; weight split (Wq/Wk plain, Wv transposed) -----
__global__ __launch_bounds__(256) void k_prep(
    const int* __restrict__ inp, const float* __restrict__ wemb,
    const float* __restrict__ pemb, const float* __restrict__ gamma,
    const float* __restrict__ beta, f16* __restrict__ Xhi, f16* __restrict__ Xlo,
    const float* __restrict__ Wq, const float* __restrict__ Wk,
    const float* __restrict__ Wv, f16* __restrict__ Wqh, f16* __restrict__ Wql,
    f16* __restrict__ Wkh, f16* __restrict__ Wkl, f16* __restrict__ Wvt)
{
  int bid = blockIdx.x;
  int tid = threadIdx.x;
  __shared__ float red[10];
  __shared__ float Lt[64][65];
  if (bid >= NR) {
    int t  = bid - NR;           // 0..191
    int mz = t >> 6;             // 0=Wq 1=Wk 2=Wv
    int tt = t & 63;
    if (mz < 2) {                // ---- Wq/Wk: plain hi/lo split, keep [d][h] layout ----
      const float* W = mz ? Wk : Wq;
      f16* Oh = mz ? Wkh : Wqh;
      f16* Ol = mz ? Wkl : Wql;
      #pragma unroll
      for (int p = 0; p < 4; p++) {
        size_t base = (size_t)tt * 4096 + p * 1024 + tid * 4;
        float4 v = *(const float4*)&W[base];
        f16 h0 = (f16)v.x, h1 = (f16)v.y, h2 = (f16)v.z, h3 = (f16)v.w;
        hv4 hi = {h0, h1, h2, h3};
        hv4 lo = {(f16)(v.x - (float)h0), (f16)(v.y - (float)h1),
                  (f16)(v.z - (float)h2), (f16)(v.w - (float)h3)};
        *(hv4*)&Oh[base] = hi;
        *(hv4*)&Ol[base] = lo;
      }
      return;
    }
    // ---- Wv: 64x64 LDS-tiled transpose -> Wvt[h][d] ----
    int tr = tt >> 3, tc = tt & 7;
    int rr = tid >> 4;           // 0..15
    int c4 = (tid & 15) * 4;
    #pragma unroll
    for (int p = 0; p < 4; p++) {
      float4 v = *(const float4*)&Wv[(size_t)(tr * 64 + p * 16 + rr) * DD + tc * 64 + c4];
      Lt[p * 16 + rr][c4 + 0] = v.x; Lt[p * 16 + rr][c4 + 1] = v.y;
      Lt[p * 16 + rr][c4 + 2] = v.z; Lt[p * 16 + rr][c4 + 3] = v.w;
    }
    __syncthreads();
    #pragma unroll
    for (int p = 0; p < 4; p++) {
      int dl = p * 16 + rr;
      float v0 = Lt[c4 + 0][dl], v1 = Lt[c4 + 1][dl];
      float v2 = Lt[c4 + 2][dl], v3 = Lt[c4 + 3][dl];
      size_t o = (size_t)(tc * 64 + dl) * DD + tr * 64 + c4;
      *(hv4*)&Wvt[o] = (hv4){(f16)v0, (f16)v1, (f16)v2, (f16)v3};
    }
    return;
  }
  // ---- embedding + layernorm -> split fp16 X ----
  int row = bid;
  int s   = row & (SS - 1);
  int tok = inp[row];
  float2 w = ((const float2*)(wemb + (size_t)tok * DD))[tid];
  float2 p = ((const float2*)(pemb + (size_t)s   * DD))[tid];
  float ex = w.x + p.x, ey = w.y + p.y;
  float sum = ex + ey, ssq = ex*ex + ey*ey;
  #pragma unroll
  for (int off = 32; off > 0; off >>= 1) {
    sum += __shfl_down(sum, off, 64);
    ssq += __shfl_down(ssq, off, 64);
  }
  int wv = tid >> 6, ln = tid & 63;
  if (ln == 0) { red[wv] = sum; red[4 + wv] = ssq; }
  __syncthreads();
  if (tid == 0) {
    float s4 = red[0] + red[1] + red[2] + red[3];
    float q4 = red[4] + red[5] + red[6] + red[7];
    float mean = s4 * (1.0f / DD);
    float var  = q4 * (1.0f / DD) - mean * mean;
    red[8] = mean; red[9] = rsqrtf(var + 1e-5f);
  }
  __syncthreads();
  float mean = red[8], rstd = red[9];
  float2 g  = ((const float2*)gamma)[tid];
  float2 bt = ((const float2*)beta)[tid];
  float ox = (ex - mean) * rstd * g.x + bt.x;
  float oy = (ey - mean) * rstd * g.y + bt.y;
  f16 hx = (f16)ox, hy = (f16)oy;
  f16 lx = (f16)(ox - (float)hx), ly = (f16)(oy - (float)hy);
  ((hv2*)(Xhi + (size_t)row * DD))[tid] = (hv2){hx, hy};
  ((hv2*)(Xlo + (size_t)row * DD))[tid] = (hv2){lx, ly};
}

// ---------------- K2a: Mt[e][d] = sum_h Wk[e][h] Wq[d][h] (3-term split) -----
__global__ __launch_bounds__(256, 2) void k_mt(
    const f16* __restrict__ Wkh, const f16* __restrict__ Wkl,
    const f16* __restrict__ Wqh, const f16* __restrict__ Wql,
    f16* __restrict__ Mthi, f16* __restrict__ Mtlo)
{
  __shared__ __align__(16) char Ah[16384], Al[16384], Bh[16384], Bl[16384];
  int tid = threadIdx.x, wv = tid >> 6, ln = tid & 63;
  int mw = wv & 1, nw = wv >> 1;
  int n0 = blockIdx.x * 128;   // d
  int m0 = blockIdx.y * 128;   // e
  f32x4 acc[4][4];
  #pragma unroll
  for (int i = 0; i < 4; i++)
    #pragma unroll
    for (int j = 0; j < 4; j++) acc[i][j] = (f32x4)(0.0f);
  int quad = ln >> 4, l15 = ln & 15;
  for (int k0 = 0; k0 < DD; k0 += 64) {
    __syncthreads();
    stage128((const char*)(Wkh + (size_t)m0 * DD + k0), 1024, Ah, wv, ln);
    stage128((const char*)(Wkl + (size_t)m0 * DD + k0), 1024, Al, wv, ln);
    stage128((const char*)(Wqh + (size_t)n0 * DD + k0), 1024, Bh, wv, ln);
    stage128((const char*)(Wql + (size_t)n0 * DD + k0), 1024, Bl, wv, ln);
    __syncthreads();
    #pragma unroll
    for (int ks = 0; ks < 2; ks++) {
      int kc = ks * 4 + quad;
      half8 ah[4], al[4], bh[4], bl[4];
      #pragma unroll
      for (int t = 0; t < 4; t++) {
        ah[t] = frag_ld(Ah, mw * 64 + t * 16 + l15, kc);
        al[t] = frag_ld(Al, mw * 64 + t * 16 + l15, kc);
        bh[t] = frag_ld(Bh, nw * 64 + t * 16 + l15, kc);
        bl[t] = frag_ld(Bl, nw * 64 + t * 16 + l15, kc);
      }
      #pragma unroll
      for (int i = 0; i < 4; i++)
        #pragma unroll
        for (int j = 0; j < 4; j++) {
          acc[i][j] = MF(ah[i], bh[j], acc[i][j]);
          acc[i][j] = MF(ah[i], bl[j], acc[i][j]);
          acc[i][j] = MF(al[i], bh[j], acc[i][j]);
        }
    }
  }
  #pragma unroll
  for (int i = 0; i < 4; i++)
    #pragma unroll
    for (int j = 0; j < 4; j++)
      #pragma unroll
      for (int rg = 0; rg < 4; rg++) {
        int gm = m0 + mw * 64 + i * 16 + quad * 4 + rg;   // e
        int gn = n0 + nw * 64 + j * 16 + l15;             // d
        size_t o = (size_t)gm * DD + gn;
        float v = acc[i][j][rg];
        f16 h = (f16)v;
        Mthi[o] = h; Mtlo[o] = (f16)(v - (float)h);
      }
}

// ---------------- K2b: Sq = X * Mt^T (split x split, 3-term) ----------------
// 8 waves, 128x128 tile: 64KB LDS -> 2 blocks/CU (4 waves/SIMD).
__global__ __launch_bounds__(512, 4) void k_projm(
    const f16* __restrict__ Xhi, const f16* __restrict__ Xlo,
    const f16* __restrict__ Mthi, const f16* __restrict__ Mtlo,
    f16* __restrict__ Sqhi, f16* __restrict__ Sqlo)
{
  __shared__ __align__(16) char Ah[16384], Al[16384], Bh[16384], Bl[16384];
  int tid = threadIdx.x, wv = tid >> 6, ln = tid & 63;
  int mw = wv & 1, nw = wv >> 1;       // nw in [0,4): 32-col slice
  // swizzle: L = (y&7) + 8x + 32*(y>>3); the 4 same-m0 blocks share an XCD
  int L = blockIdx.x;
  int xb = (L >> 3) & 3;
  int y  = ((L >> 5) << 3) + (L & 7);
  int n0 = xb * 128;  // e
  int m0 = y * 128;   // s
  f32x4 acc[4][2];
  #pragma unroll
  for (int i = 0; i < 4; i++)
    #pragma unroll
    for (int j = 0; j < 2; j++) acc[i][j] = (f32x4)(0.0f);
  int quad = ln >> 4, l15 = ln & 15;
  for (int k0 = 0; k0 < DD; k0 += 64) {
    __syncthreads();
    stage16k_512((const char*)(Xhi  + (size_t)m0 * DD + k0), 1024, Ah);
    stage16k_512((const char*)(Xlo  + (size_t)m0 * DD + k0), 1024, Al);
    stage16k_512((const char*)(Mthi + (size_t)n0 * DD + k0), 1024, Bh);
    stage16k_512((const char*)(Mtlo + (size_t)n0 * DD + k0), 1024, Bl);
    __syncthreads();
    #pragma unroll
    for (int ks = 0; ks < 2; ks++) {
      int kc = ks * 4 + quad;
      half8 ah[4], al[4], bh[2], bl[2];
      #pragma unroll
      for (int t = 0; t < 4; t++) {
        ah[t] = frag_ld(Ah, mw * 64 + t * 16 + l15, kc);
        al[t] = frag_ld(Al, mw * 64 + t * 16 + l15, kc);
      }
      #pragma unroll
      for (int t = 0; t < 2; t++) {
        bh[t] = frag_ld(Bh, nw * 32 + t * 16 + l15, kc);
        bl[t] = frag_ld(Bl, nw * 32 + t * 16 + l15, kc);
      }
      #pragma unroll
      for (int i = 0; i < 4; i++)
        #pragma unroll
        for (int j = 0; j < 2; j++) {
          acc[i][j] = MF(ah[i], bh[j], acc[i][j]);
          acc[i][j] = MF(ah[i], bl[j], acc[i][j]);
          acc[i][j] = MF(al[i], bh[j], acc[i][j]);
        }
    }
  }
  #pragma unroll
  for (int i = 0; i < 4; i++)
    #pragma unroll
    for (int j = 0; j < 2; j++)
      #pragma unroll
      for (int rg = 0; rg < 4; rg++) {
        int gm = m0 + mw * 64 + i * 16 + quad * 4 + rg;
        int gn = n0 + nw * 32 + j * 16 + l15;
        size_t o = (size_t)gm * DD + gn;
        float v = acc[i][j][rg];
        f16 h = (f16)v;
        Sqhi[o] = h; Sqlo[o] = (f16)(v - (float)h);
      }
}

// ---------------- K3: Vt GEMM (plain fp16): Vt[d][s], ping-pong pipelined ----------
__global__ __launch_bounds__(256, 2) void k_vt(
    const f16* __restrict__ Wvt, const f16* __restrict__ Xhi, f16* __restrict__ Vt)
{
  __shared__ __align__(16) char Ah[2][16384], Bh[2][16384];
  int tid = threadIdx.x, wv = tid >> 6, ln = tid & 63;
  int mw = wv & 1, nw = wv >> 1;
  // XCD-bijective swizzle (nwg=1024): XCD c owns s-tiles [c*32,(c+1)*32), all 4 d-tiles
  int orig = blockIdx.x;
  int L = (orig & 7) * 128 + (orig >> 3);
  int c = L >> 7, t = L & 127;
  int m0 = (t & 3) * 128;                // d
  int n0 = (c * 32 + (t >> 2)) * 128;    // s
  f32x4 acc[4][4];
  #pragma unroll
  for (int i = 0; i < 4; i++)
    #pragma unroll
    for (int j = 0; j < 4; j++) acc[i][j] = (f32x4)(0.0f);
  int quad = ln >> 4, l15 = ln & 15;
  // prologue
  stage128((const char*)(Wvt + (size_t)m0 * DD), 1024, Ah[0], wv, ln);
  stage128((const char*)(Xhi + (size_t)n0 * DD), 1024, Bh[0], wv, ln);
  for (int k0 = 0; k0 < DD; k0 += 64) {
    int cur = (k0 >> 6) & 1;
    __builtin_amdgcn_s_barrier();
    __builtin_amdgcn_sched_barrier(0);
    if (k0 + 64 < DD) {
      stage128((const char*)(Wvt + (size_t)m0 * DD + k0 + 64), 1024, Ah[cur ^ 1], wv, ln);
      stage128((const char*)(Xhi + (size_t)n0 * DD + k0 + 64), 1024, Bh[cur ^ 1], wv, ln);
      asm volatile("s_waitcnt vmcnt(8)" ::: "memory");
    } else {
      asm volatile("s_waitcnt vmcnt(0)" ::: "memory");
    }
    __builtin_amdgcn_s_barrier();
    __builtin_amdgcn_sched_barrier(0);
    #pragma unroll
    for (int ks = 0; ks < 2; ks++) {
      int kc = ks * 4 + quad;
      half8 a[4], b[4];
      #pragma unroll
      for (int tt = 0; tt < 4; tt++) {
        a[tt] = frag_ld(Ah[cur], mw * 64 + tt * 16 + l15, kc);
        b[tt] = frag_ld(Bh[cur], nw * 64 + tt * 16 + l15, kc);
      }
      #pragma unroll
      for (int i = 0; i < 4; i++)
        #pragma unroll
        for (int j = 0; j < 4; j++) acc[i][j] = MF(a[i], b[j], acc[i][j]);
    }
  }
  #pragma unroll
  for (int i = 0; i < 4; i++)
    #pragma unroll
    for (int j = 0; j < 4; j++)
      #pragma unroll
      for (int rg = 0; rg < 4; rg++) {
        int gm = m0 + mw * 64 + i * 16 + quad * 4 + rg;   // d
        int gn = n0 + nw * 64 + j * 16 + l15;             // s
        Vt[(size_t)gm * NR + gn] = (f16)acc[i][j][rg];
      }
}

// ---------------- K4: fused S = Sq X^T / sqrt(D) + row softmax -> P fp16 -------------
// 512 threads, block = 64 q x 1024 k x 1 batch. 80 KB LDS -> 2 blocks/CU naturally.
// launch_bounds (512,2): do NOT force 4 waves/EU — that caps regs and spills the
// 128-float accumulator to scratch (round-8 regression: VGPR 64, 1.3 GB scratch).
// 8 sub-phases per k0 (32-key B slices), B ping-pong + counted vmcnt(4)/(6);
// A staged to LDS, prefetched one k0 ahead at r==7, hoisted to regs at r==0.
__global__ __launch_bounds__(512, 2) void k_qk(
    const f16* __restrict__ Sqhi, const f16* __restrict__ Sqlo,
    const f16* __restrict__ Xhi, const f16* __restrict__ Xlo,
    f16* __restrict__ Pws, f16* __restrict__ Pd)
{
  __shared__ __align__(16) char Ah[8192], Al[8192];
  __shared__ __align__(16) char Bh[2][16384], Bl[2][16384];   // [buf][q4*4096 + ...]
  int tid = threadIdx.x, wv = tid >> 6, ln = tid & 63;
  int rowg = wv & 1, qd = wv >> 1;
  // swizzle decode: L = g*128 + j*8 + xcd;  z = g*8 + xcd, m0 = j*64
  int L = blockIdx.x;
  int g  = L >> 7;
  int rr = L & 127;
  int z  = g * 8 + (rr & 7);
  int m0 = (rr >> 3) * 64;
  size_t zr = (size_t)z * SS;
  f32x4 acc[2][16];
  #pragma unroll
  for (int i = 0; i < 2; i++)
    #pragma unroll
    for (int j = 0; j < 16; j++) acc[i][j] = (f32x4)(0.0f);
  int quad = ln >> 4, l15 = ln & 15;

  // prologue: A(k0=0) then B(k0=0, r=0) into buf 0 -> in flight: A2 + B4
  stage8k_512((const char*)(Sqhi + (zr + m0) * DD), 1024, Ah);
  stage8k_512((const char*)(Sqlo + (zr + m0) * DD), 1024, Al);
  stageB32(Xhi, zr + 0, 0, Bh[0]);
  stageB32(Xlo, zr + 0, 0, Bl[0]);

  half8 afh[2][2], afl[2][2];   // A-fragments for the current k0, reused across r
  for (int k0 = 0; k0 < DD; k0 += 64) {
    #pragma unroll
    for (int r = 0; r < 8; r++) {
      // barrier1: all waves done reading buf[(r+1)&1] (from phase p-1) before overwrite
      __builtin_amdgcn_s_barrier();
      __builtin_amdgcn_sched_barrier(0);
      bool lastPhase = (k0 == DD - 64 && r == 7);
      if (!lastPhase) {
        int nk0 = (r == 7) ? k0 + 64 : k0;
        int nr  = (r + 1) & 7;
        stageB32(Xhi, zr + nr * 32, nk0, Bh[(r + 1) & 1]);
        stageB32(Xlo, zr + nr * 32, nk0, Bl[(r + 1) & 1]);
        if (r == 7) {
          // prefetch A for next k0 (single buffer: only reader is next r==0 hoist)
          stage8k_512((const char*)(Sqhi + (zr + m0) * DD + k0 + 64), 1024, Ah);
          stage8k_512((const char*)(Sqlo + (zr + m0) * DD + k0 + 64), 1024, Al);
          asm volatile("s_waitcnt vmcnt(6)" ::: "memory");
        } else {
          asm volatile("s_waitcnt vmcnt(4)" ::: "memory");
        }
      } else {
        asm volatile("s_waitcnt vmcnt(0)" ::: "memory");
      }
      __builtin_amdgcn_s_barrier();
      __builtin_amdgcn_sched_barrier(0);
      if (r == 0) {   // hoist A-fragments: 8 ds_reads per k0
        #pragma unroll
        for (int ks = 0; ks < 2; ks++)
          #pragma unroll
          for (int i = 0; i < 2; i++) {
            afh[ks][i] = frag_ld(Ah, rowg * 32 + i * 16 + l15, ks * 4 + quad);
            afl[ks][i] = frag_ld(Al, rowg * 32 + i * 16 + l15, ks * 4 + quad);
          }
      }
      const char* Bhc = Bh[r & 1] + qd * 4096;
      const char* Blc = Bl[r & 1] + qd * 4096;
      #pragma unroll
      for (int ks = 0; ks < 2; ks++) {
        int kc = ks * 4 + quad;
        #pragma unroll
        for (int jj = 0; jj < 2; jj++) {
          half8 bh = frag_ld(Bhc, jj * 16 + l15, kc);
          half8 bl = frag_ld(Blc, jj * 16 + l15, kc);
          #pragma unroll
          for (int i = 0; i < 2; i++) {
            acc[i][r * 2 + jj] = MF(afh[ks][i], bh, acc[i][r * 2 + jj]);
            acc[i][r * 2 + jj] = MF(afh[ks][i], bl, acc[i][r * 2 + jj]);
            acc[i][r * 2 + jj] = MF(afl[ks][i], bh, acc[i][r * 2 + jj]);
          }
        }
      }
    }
  }
  __syncthreads();   // all MFMA done -> B buffers free for red alias
  float* redm = (float*)&Bh[0][0];     // [4][64] -> qd*64 + row
  float* reds = redm + 256;

  // ---- fused softmax over the full 1024-key row ----
  const float scale = 0.044194173824159216f;   // 1/sqrt(512)
  float mx[2][4];
  #pragma unroll
  for (int i = 0; i < 2; i++)
    #pragma unroll
    for (int rg = 0; rg < 4; rg++) mx[i][rg] = -3.0e38f;
  #pragma unroll
  for (int i = 0; i < 2; i++)
    #pragma unroll
    for (int j = 0; j < 16; j++)
      #pragma unroll
      for (int rg = 0; rg < 4; rg++) {
        acc[i][j][rg] *= scale;
        mx[i][rg] = fmaxf(mx[i][rg], acc[i][j][rg]);
      }
  #pragma unroll
  for (int off = 1; off < 16; off <<= 1)
    #pragma unroll
    for (int i = 0; i < 2; i++)
      #pragma unroll
      for (int rg = 0; rg < 4; rg++)
        mx[i][rg] = fmaxf(mx[i][rg], __shfl_xor(mx[i][rg], off, 64));
  if (l15 == 0) {
    #pragma unroll
    for (int i = 0; i < 2; i++)
      #pragma unroll
      for (int rg = 0; rg < 4; rg++)
        redm[qd * 64 + rowg * 32 + i * 16 + quad * 4 + rg] = mx[i][rg];
  }
  __syncthreads();
  float fm[2][4], sum[2][4];
  #pragma unroll
  for (int i = 0; i < 2; i++)
    #pragma unroll
    for (int rg = 0; rg < 4; rg++) {
      int row = rowg * 32 + i * 16 + quad * 4 + rg;
      fm[i][rg] = fmaxf(fmaxf(redm[row], redm[64 + row]),
                        fmaxf(redm[128 + row], redm[192 + row]));
      sum[i][rg] = 0.0f;
    }
  #pragma unroll
  for (int i = 0; i < 2; i++)
    #pragma unroll
    for (int j = 0; j < 16; j++)
      #pragma unroll
      for (int rg = 0; rg < 4; rg++) {
        float e = __expf(acc[i][j][rg] - fm[i][rg]);
        acc[i][j][rg] = e;
        sum[i][rg] += e;
      }
  #pragma unroll
  for (int off = 1; off < 16; off <<= 1)
    #pragma unroll
    for (int i = 0; i < 2; i++)
      #pragma unroll
      for (int rg = 0; rg < 4; rg++)
        sum[i][rg] += __shfl_xor(sum[i][rg], off, 64);
  if (l15 == 0) {
    #pragma unroll
    for (int i = 0; i < 2; i++)
      #pragma unroll
      for (int rg = 0; rg < 4; rg++)
        reds[qd * 64 + rowg * 32 + i * 16 + quad * 4 + rg] = sum[i][rg];
  }
  __syncthreads();
  float inv[2][4];
  #pragma unroll
  for (int i = 0; i < 2; i++)
    #pragma unroll
    for (int rg = 0; rg < 4; rg++) {
      int row = rowg * 32 + i * 16 + quad * 4 + rg;
      inv[i][rg] = 1.0f / (reds[row] + reds[64 + row] + reds[128 + row] + reds[192 + row]);
    }
  f16* Pb = (z < CH) ? Pws : Pd;
  size_t zo = (size_t)((z < CH) ? z : z - CH);
  #pragma unroll
  for (int i = 0; i < 2; i++)
    #pragma unroll
    for (int j = 0; j < 16; j++)
      #pragma unroll
      for (int rg = 0; rg < 4; rg++) {
        int row = rowg * 32 + i * 16 + quad * 4 + rg;
        int col = qd * 256 + j * 16 + l15;
        Pb[(zo * SS + m0 + row) * SS + col] = (f16)(acc[i][j][rg] * inv[i][rg]);
      }
}

// ---------------- K6: O = P V  (fp16 MFMA), ping-pong pipelined, XCD swizzle --------
__global__ __launch_bounds__(256, 2) void k_pv(
    const f16* __restrict__ P, const f16* __restrict__ Vt, float* __restrict__ O,
    int zoff)
{
  __shared__ __align__(16) char Ah[2][16384], Bh[2][16384];
  int tid = threadIdx.x, wv = tid >> 6, ln = tid & 63;
  int mw = wv & 1, nw = wv >> 1;
  // XCD-bijective swizzle (nwg=512): XCD c owns batches {2c, 2c+1}
  int orig = blockIdx.x;
  int L = (orig & 7) * 64 + (orig >> 3);
  int c = L >> 6, t = L & 63;
  int zl = 2 * c + (t >> 5);          // 0..15
  int m0 = ((t >> 2) & 7) * 128;      // query (within batch)
  int n0 = (t & 3) * 128;             // d_out
  int b  = zoff + zl;                 // global batch
  const char* Pt = (const char*)(P + ((size_t)zl * SS + m0) * SS);
  const char* Vb = (const char*)(Vt + (size_t)n0 * NR + (size_t)b * SS);
  f32x4 acc[4][4];
  #pragma unroll
  for (int i = 0; i < 4; i++)
    #pragma unroll
    for (int j = 0; j < 4; j++) acc[i][j] = (f32x4)(0.0f);
  int quad = ln >> 4, l15 = ln & 15;
  // prologue
  stage128(Pt, 2048, Ah[0], wv, ln);
  stage128(Vb, NR * 2, Bh[0], wv, ln);
  for (int k0 = 0; k0 < SS; k0 += 64) {
    int cur = (k0 >> 6) & 1;
    __builtin_amdgcn_s_barrier();
    __builtin_amdgcn_sched_barrier(0);
    if (k0 + 64 < SS) {
      stage128(Pt + (k0 + 64) * 2, 2048, Ah[cur ^ 1], wv, ln);
      stage128(Vb + (k0 + 64) * 2, NR * 2, Bh[cur ^ 1], wv, ln);
      asm volatile("s_waitcnt vmcnt(8)" ::: "memory");
    } else {
      asm volatile("s_waitcnt vmcnt(0)" ::: "memory");
    }
    __builtin_amdgcn_s_barrier();
    __builtin_amdgcn_sched_barrier(0);
    #pragma unroll
    for (int ks = 0; ks < 2; ks++) {
      int kc = ks * 4 + quad;
      half8 a[4], bf[4];
      #pragma unroll
      for (int tt = 0; tt < 4; tt++) {
        a[tt]  = frag_ld(Ah[cur], mw * 64 + tt * 16 + l15, kc);
        bf[tt] = frag_ld(Bh[cur], nw * 64 + tt * 16 + l15, kc);
      }
      #pragma unroll
      for (int i = 0; i < 4; i++)
        #pragma unroll
        for (int j = 0; j < 4; j++) acc[i][j] = MF(a[i], bf[j], acc[i][j]);
    }
  }
  #pragma unroll
  for (int i = 0; i < 4; i++)
    #pragma unroll
    for (int j = 0; j < 4; j++)
      #pragma unroll
      for (int rg = 0; rg < 4; rg++) {
        int gm = m0 + mw * 64 + i * 16 + quad * 4 + rg;
        int gn = n0 + nw * 64 + j * 16 + l15;
        O[((size_t)b * SS + gm) * DD + gn] = acc[i][j][rg];
      }
}

extern "C" void kernel_launch(void* const* d_in, const int* in_sizes, int n_in,
                              void* d_out, int out_size, void* d_ws, size_t ws_size,
                              hipStream_t stream) {
  const int*   inp   = (const int*)d_in[0];
  const float* wemb  = (const float*)d_in[1];
  const float* pemb  = (const float*)d_in[2];
  const float* gamma = (const float*)d_in[3];
  const float* beta  = (const float*)d_in[4];
  const float* Wk    = (const float*)d_in[5];
  const float* Wq    = (const float*)d_in[6];
  const float* Wv    = (const float*)d_in[7];

  // ws (192 MiB): [Xhi 32M][Xlo 32M][Sqhi 32M][Sqlo 32M][Vt 32M][Pws 32M]
  // P batches 0..15 -> Pws; batches 16..31 -> d_out[0,32M).
  // k_pv runs b=16..31 first (reads d_out[0,32M), writes d_out[32,64M)),
  // then b=0..15 (reads Pws, writes d_out[0,32M)). Stream order makes this safe.
  char* ws = (char*)d_ws;
  f16* Xhi  = (f16*)ws;
  f16* Xlo  = (f16*)(ws + ((size_t)32 << 20));
  f16* Sqhi = (f16*)(ws + ((size_t)64 << 20));
  f16* Sqlo = (f16*)(ws + ((size_t)96 << 20));
  f16* Vt   = (f16*)(ws + ((size_t)128 << 20));
  f16* Pws  = (f16*)(ws + ((size_t)160 << 20));
  f16* Pd   = (f16*)d_out;

  f16* Wqh  = (f16*)d_out;
  f16* Wql  = Wqh + (size_t)DD * DD;
  f16* Wkh  = Wql + (size_t)DD * DD;
  f16* Wkl  = Wkh + (size_t)DD * DD;
  f16* Wvt  = Wkl + (size_t)DD * DD;
  f16* Mthi = Wvt + (size_t)DD * DD;
  f16* Mtlo = Mthi + (size_t)DD * DD;

  k_prep<<<NR + 192, 256, 0, stream>>>(inp, wemb, pemb, gamma, beta, Xhi, Xlo,
                                       Wq, Wk, Wv, Wqh, Wql, Wkh, Wkl, Wvt);
  k_mt<<<dim3(DD / 128, DD / 128), 256, 0, stream>>>(Wkh, Wkl, Wqh, Wql, Mthi, Mtlo);
  k_projm<<<1024, 512, 0, stream>>>(Xhi, Xlo, Mthi, Mtlo, Sqhi, Sqlo);
  k_vt<<<1024, 256, 0, stream>>>(Wvt, Xhi, Vt);
  k_qk<<<512, 512, 0, stream>>>(Sqhi, Sqlo, Xhi, Xlo, Pws, Pd);
  k_pv<<<512, 256, 0, stream>>>(Pd,  Vt, (float*)d_out, CH);
  k_pv<<<512, 256, 0, stream>>>(Pws, Vt, (float*)d_out, 0);
}

// Round 10
// 416.227 us; speedup vs baseline: 1.6270x; 1.0229x over previous
//
#include <hip/hip_runtime.h>
#include <math.h>

typedef _Float16 f16;
typedef _Float16 half8 __attribute__((ext_vector_type(8)));
typedef _Float16 hv2 __attribute__((ext_vector_type(2)));
typedef _Float16 hv4 __attribute__((ext_vector_type(4)));
typedef float f32x4 __attribute__((ext_vector_type(4)));
typedef __attribute__((address_space(1))) const unsigned int gu32;
typedef __attribute__((address_space(3))) unsigned int lu32;

#define BB 32
#define SS 1024
#define DD 512
#define NR (BB*SS)   // 32768
#define CH 16

// ---------- m97-style staging helpers (128B rows, 16B chunks, xor-swizzle row&7) ----------
__device__ __forceinline__ void stage128(const char* g, int ldb, char* lds,
                                         int wv, int ln) {
  #pragma unroll
  for (int r = 0; r < 4; r++) {
    int slot = r * 256 + wv * 64 + ln;
    int row = slot >> 3, cp = slot & 7;
    int c = cp ^ (row & 7);
    const char* gp = g + (size_t)row * ldb + (c << 4);
    char* lp = lds + ((slot - ln) << 4);
    __builtin_amdgcn_global_load_lds((gu32*)gp, (lu32*)lp, 16, 0, 0);
  }
}

// 128 rows x 128B (16KB) staged by 512 threads, two 16B slots each
__device__ __forceinline__ void stage16k_512(const char* g, int ldb, char* lds) {
  int tid = threadIdx.x;
  #pragma unroll
  for (int r = 0; r < 2; r++) {
    int slot = r * 512 + tid;
    int row = slot >> 3, cp = slot & 7;
    int c = cp ^ (row & 7);
    const char* gp = g + (size_t)row * ldb + (c << 4);
    char* lp = lds + ((slot - (tid & 63)) << 4);
    __builtin_amdgcn_global_load_lds((gu32*)gp, (lu32*)lp, 16, 0, 0);
  }
}

// k_qk A-stage: 32 rows x 128B (4KB) by 256 threads, one 16B slot each
__device__ __forceinline__ void stageA32(const f16* Sq, size_t rowbase, int k0,
                                         char* lds) {
  int tid = threadIdx.x;
  int slot = tid;                  // 0..255
  int row = slot >> 3, cp = slot & 7;
  int c = cp ^ (row & 7);
  const char* gp = (const char*)(Sq + (rowbase + (size_t)row) * DD + k0) + (c << 4);
  char* lp = lds + ((slot - (tid & 63)) << 4);
  __builtin_amdgcn_global_load_lds((gu32*)gp, (lu32*)lp, 16, 0, 0);
}

// k_qk B-stage: ONE WAVE stages its own 32-key x 64-kdim slice (4KB), 4 slots/lane
__device__ __forceinline__ void stageB32w(const f16* X, size_t rowbase, int k0,
                                          char* BsetQd) {
  int ln = threadIdx.x & 63;
  const char* g = (const char*)(X + rowbase * DD + k0);
  #pragma unroll
  for (int r = 0; r < 4; r++) {
    int slot = r * 64 + ln;
    int row = slot >> 3, cp = slot & 7;
    int c = cp ^ (row & 7);
    const char* gp = g + (size_t)row * 1024 + (c << 4);
    char* lp = BsetQd + ((slot - ln) << 4);
    __builtin_amdgcn_global_load_lds((gu32*)gp, (lu32*)lp, 16, 0, 0);
  }
}

__device__ __forceinline__ half8 frag_ld(const char* lds, int row, int kc) {
  return *(const half8*)(lds + row * 128 + ((kc ^ (row & 7)) << 4));
}

__device__ __forceinline__ f32x4 MF(half8 a, half8 b, f32x4 c) {
  return __builtin_amdgcn_mfma_f32_16x16x32_f16(a, b, c, 0, 0, 0);
}

// ---------------- K1: merged embedding+LN; weight split (Wq/Wk plain, Wv transposed) -----
__global__ __launch_bounds__(256) void k_prep(
    const int* __restrict__ inp, const float* __restrict__ wemb,
    const float* __restrict__ pemb, const float* __restrict__ gamma,
    const float* __restrict__ beta, f16* __restrict__ Xhi, f16* __restrict__ Xlo,
    const float* __restrict__ Wq, const float* __restrict__ Wk,
    const float* __restrict__ Wv, f16* __restrict__ Wqh, f16* __restrict__ Wql,
    f16* __restrict__ Wkh, f16* __restrict__ Wkl, f16* __restrict__ Wvt)
{
  int bid = blockIdx.x;
  int tid = threadIdx.x;
  __shared__ float red[10];
  __shared__ float Lt[64][65];
  if (bid >= NR) {
    int t  = bid - NR;           // 0..191
    int mz = t >> 6;             // 0=Wq 1=Wk 2=Wv
    int tt = t & 63;
    if (mz < 2) {                // ---- Wq/Wk: plain hi/lo split, keep [d][h] layout ----
      const float* W = mz ? Wk : Wq;
      f16* Oh = mz ? Wkh : Wqh;
      f16* Ol = mz ? Wkl : Wql;
      #pragma unroll
      for (int p = 0; p < 4; p++) {
        size_t base = (size_t)tt * 4096 + p * 1024 + tid * 4;
        float4 v = *(const float4*)&W[base];
        f16 h0 = (f16)v.x, h1 = (f16)v.y, h2 = (f16)v.z, h3 = (f16)v.w;
        hv4 hi = {h0, h1, h2, h3};
        hv4 lo = {(f16)(v.x - (float)h0), (f16)(v.y - (float)h1),
                  (f16)(v.z - (float)h2), (f16)(v.w - (float)h3)};
        *(hv4*)&Oh[base] = hi;
        *(hv4*)&Ol[base] = lo;
      }
      return;
    }
    // ---- Wv: 64x64 LDS-tiled transpose -> Wvt[h][d] ----
    int tr = tt >> 3, tc = tt & 7;
    int rr = tid >> 4;           // 0..15
    int c4 = (tid & 15) * 4;
    #pragma unroll
    for (int p = 0; p < 4; p++) {
      float4 v = *(const float4*)&Wv[(size_t)(tr * 64 + p * 16 + rr) * DD + tc * 64 + c4];
      Lt[p * 16 + rr][c4 + 0] = v.x; Lt[p * 16 + rr][c4 + 1] = v.y;
      Lt[p * 16 + rr][c4 + 2] = v.z; Lt[p * 16 + rr][c4 + 3] = v.w;
    }
    __syncthreads();
    #pragma unroll
    for (int p = 0; p < 4; p++) {
      int dl = p * 16 + rr;
      float v0 = Lt[c4 + 0][dl], v1 = Lt[c4 + 1][dl];
      float v2 = Lt[c4 + 2][dl], v3 = Lt[c4 + 3][dl];
      size_t o = (size_t)(tc * 64 + dl) * DD + tr * 64 + c4;
      *(hv4*)&Wvt[o] = (hv4){(f16)v0, (f16)v1, (f16)v2, (f16)v3};
    }
    return;
  }
  // ---- embedding + layernorm -> split fp16 X ----
  int row = bid;
  int s   = row & (SS - 1);
  int tok = inp[row];
  float2 w = ((const float2*)(wemb + (size_t)tok * DD))[tid];
  float2 p = ((const float2*)(pemb + (size_t)s   * DD))[tid];
  float ex = w.x + p.x, ey = w.y + p.y;
  float sum = ex + ey, ssq = ex*ex + ey*ey;
  #pragma unroll
  for (int off = 32; off > 0; off >>= 1) {
    sum += __shfl_down(sum, off, 64);
    ssq += __shfl_down(ssq, off, 64);
  }
  int wv = tid >> 6, ln = tid & 63;
  if (ln == 0) { red[wv] = sum; red[4 + wv] = ssq; }
  __syncthreads();
  if (tid == 0) {
    float s4 = red[0] + red[1] + red[2] + red[3];
    float q4 = red[4] + red[5] + red[6] + red[7];
    float mean = s4 * (1.0f / DD);
    float var  = q4 * (1.0f / DD) - mean * mean;
    red[8] = mean; red[9] = rsqrtf(var + 1e-5f);
  }
  __syncthreads();
  float mean = red[8], rstd = red[9];
  float2 g  = ((const float2*)gamma)[tid];
  float2 bt = ((const float2*)beta)[tid];
  float ox = (ex - mean) * rstd * g.x + bt.x;
  float oy = (ey - mean) * rstd * g.y + bt.y;
  f16 hx = (f16)ox, hy = (f16)oy;
  f16 lx = (f16)(ox - (float)hx), ly = (f16)(oy - (float)hy);
  ((hv2*)(Xhi + (size_t)row * DD))[tid] = (hv2){hx, hy};
  ((hv2*)(Xlo + (size_t)row * DD))[tid] = (hv2){lx, ly};
}

// ---------------- K2a: Mt[e][d] = sum_h Wk[e][h] Wq[d][h] (3-term split) -----
__global__ __launch_bounds__(256, 2) void k_mt(
    const f16* __restrict__ Wkh, const f16* __restrict__ Wkl,
    const f16* __restrict__ Wqh, const f16* __restrict__ Wql,
    f16* __restrict__ Mthi, f16* __restrict__ Mtlo)
{
  __shared__ __align__(16) char Ah[16384], Al[16384], Bh[16384], Bl[16384];
  int tid = threadIdx.x, wv = tid >> 6, ln = tid & 63;
  int mw = wv & 1, nw = wv >> 1;
  int n0 = blockIdx.x * 128;   // d
  int m0 = blockIdx.y * 128;   // e
  f32x4 acc[4][4];
  #pragma unroll
  for (int i = 0; i < 4; i++)
    #pragma unroll
    for (int j = 0; j < 4; j++) acc[i][j] = (f32x4)(0.0f);
  int quad = ln >> 4, l15 = ln & 15;
  for (int k0 = 0; k0 < DD; k0 += 64) {
    __syncthreads();
    stage128((const char*)(Wkh + (size_t)m0 * DD + k0), 1024, Ah, wv, ln);
    stage128((const char*)(Wkl + (size_t)m0 * DD + k0), 1024, Al, wv, ln);
    stage128((const char*)(Wqh + (size_t)n0 * DD + k0), 1024, Bh, wv, ln);
    stage128((const char*)(Wql + (size_t)n0 * DD + k0), 1024, Bl, wv, ln);
    __syncthreads();
    #pragma unroll
    for (int ks = 0; ks < 2; ks++) {
      int kc = ks * 4 + quad;
      half8 ah[4], al[4], bh[4], bl[4];
      #pragma unroll
      for (int t = 0; t < 4; t++) {
        ah[t] = frag_ld(Ah, mw * 64 + t * 16 + l15, kc);
        al[t] = frag_ld(Al, mw * 64 + t * 16 + l15, kc);
        bh[t] = frag_ld(Bh, nw * 64 + t * 16 + l15, kc);
        bl[t] = frag_ld(Bl, nw * 64 + t * 16 + l15, kc);
      }
      #pragma unroll
      for (int i = 0; i < 4; i++)
        #pragma unroll
        for (int j = 0; j < 4; j++) {
          acc[i][j] = MF(ah[i], bh[j], acc[i][j]);
          acc[i][j] = MF(ah[i], bl[j], acc[i][j]);
          acc[i][j] = MF(al[i], bh[j], acc[i][j]);
        }
    }
  }
  #pragma unroll
  for (int i = 0; i < 4; i++)
    #pragma unroll
    for (int j = 0; j < 4; j++)
      #pragma unroll
      for (int rg = 0; rg < 4; rg++) {
        int gm = m0 + mw * 64 + i * 16 + quad * 4 + rg;   // e
        int gn = n0 + nw * 64 + j * 16 + l15;             // d
        size_t o = (size_t)gm * DD + gn;
        float v = acc[i][j][rg];
        f16 h = (f16)v;
        Mthi[o] = h; Mtlo[o] = (f16)(v - (float)h);
      }
}

// ---------------- K2b: Sq = X * Mt^T (split x split, 3-term) ----------------
// 8 waves, 128x128 tile: 64KB LDS -> 2 blocks/CU (4 waves/SIMD).
__global__ __launch_bounds__(512, 4) void k_projm(
    const f16* __restrict__ Xhi, const f16* __restrict__ Xlo,
    const f16* __restrict__ Mthi, const f16* __restrict__ Mtlo,
    f16* __restrict__ Sqhi, f16* __restrict__ Sqlo)
{
  __shared__ __align__(16) char Ah[16384], Al[16384], Bh[16384], Bl[16384];
  int tid = threadIdx.x, wv = tid >> 6, ln = tid & 63;
  int mw = wv & 1, nw = wv >> 1;       // nw in [0,4): 32-col slice
  // swizzle: L = (y&7) + 8x + 32*(y>>3); the 4 same-m0 blocks share an XCD
  int L = blockIdx.x;
  int xb = (L >> 3) & 3;
  int y  = ((L >> 5) << 3) + (L & 7);
  int n0 = xb * 128;  // e
  int m0 = y * 128;   // s
  f32x4 acc[4][2];
  #pragma unroll
  for (int i = 0; i < 4; i++)
    #pragma unroll
    for (int j = 0; j < 2; j++) acc[i][j] = (f32x4)(0.0f);
  int quad = ln >> 4, l15 = ln & 15;
  for (int k0 = 0; k0 < DD; k0 += 64) {
    __syncthreads();
    stage16k_512((const char*)(Xhi  + (size_t)m0 * DD + k0), 1024, Ah);
    stage16k_512((const char*)(Xlo  + (size_t)m0 * DD + k0), 1024, Al);
    stage16k_512((const char*)(Mthi + (size_t)n0 * DD + k0), 1024, Bh);
    stage16k_512((const char*)(Mtlo + (size_t)n0 * DD + k0), 1024, Bl);
    __syncthreads();
    #pragma unroll
    for (int ks = 0; ks < 2; ks++) {
      int kc = ks * 4 + quad;
      half8 ah[4], al[4], bh[2], bl[2];
      #pragma unroll
      for (int t = 0; t < 4; t++) {
        ah[t] = frag_ld(Ah, mw * 64 + t * 16 + l15, kc);
        al[t] = frag_ld(Al, mw * 64 + t * 16 + l15, kc);
      }
      #pragma unroll
      for (int t = 0; t < 2; t++) {
        bh[t] = frag_ld(Bh, nw * 32 + t * 16 + l15, kc);
        bl[t] = frag_ld(Bl, nw * 32 + t * 16 + l15, kc);
      }
      #pragma unroll
      for (int i = 0; i < 4; i++)
        #pragma unroll
        for (int j = 0; j < 2; j++) {
          acc[i][j] = MF(ah[i], bh[j], acc[i][j]);
          acc[i][j] = MF(ah[i], bl[j], acc[i][j]);
          acc[i][j] = MF(al[i], bh[j], acc[i][j]);
        }
    }
  }
  #pragma unroll
  for (int i = 0; i < 4; i++)
    #pragma unroll
    for (int j = 0; j < 2; j++)
      #pragma unroll
      for (int rg = 0; rg < 4; rg++) {
        int gm = m0 + mw * 64 + i * 16 + quad * 4 + rg;
        int gn = n0 + nw * 32 + j * 16 + l15;
        size_t o = (size_t)gm * DD + gn;
        float v = acc[i][j][rg];
        f16 h = (f16)v;
        Sqhi[o] = h; Sqlo[o] = (f16)(v - (float)h);
      }
}

// ---------------- K3: Vt GEMM (plain fp16): Vt[d][s], ping-pong pipelined ----------
__global__ __launch_bounds__(256, 2) void k_vt(
    const f16* __restrict__ Wvt, const f16* __restrict__ Xhi, f16* __restrict__ Vt)
{
  __shared__ __align__(16) char Ah[2][16384], Bh[2][16384];
  int tid = threadIdx.x, wv = tid >> 6, ln = tid & 63;
  int mw = wv & 1, nw = wv >> 1;
  // XCD-bijective swizzle (nwg=1024): XCD c owns s-tiles [c*32,(c+1)*32), all 4 d-tiles
  int orig = blockIdx.x;
  int L = (orig & 7) * 128 + (orig >> 3);
  int c = L >> 7, t = L & 127;
  int m0 = (t & 3) * 128;                // d
  int n0 = (c * 32 + (t >> 2)) * 128;    // s
  f32x4 acc[4][4];
  #pragma unroll
  for (int i = 0; i < 4; i++)
    #pragma unroll
    for (int j = 0; j < 4; j++) acc[i][j] = (f32x4)(0.0f);
  int quad = ln >> 4, l15 = ln & 15;
  // prologue
  stage128((const char*)(Wvt + (size_t)m0 * DD), 1024, Ah[0], wv, ln);
  stage128((const char*)(Xhi + (size_t)n0 * DD), 1024, Bh[0], wv, ln);
  for (int k0 = 0; k0 < DD; k0 += 64) {
    int cur = (k0 >> 6) & 1;
    __builtin_amdgcn_s_barrier();
    __builtin_amdgcn_sched_barrier(0);
    if (k0 + 64 < DD) {
      stage128((const char*)(Wvt + (size_t)m0 * DD + k0 + 64), 1024, Ah[cur ^ 1], wv, ln);
      stage128((const char*)(Xhi + (size_t)n0 * DD + k0 + 64), 1024, Bh[cur ^ 1], wv, ln);
      asm volatile("s_waitcnt vmcnt(8)" ::: "memory");
    } else {
      asm volatile("s_waitcnt vmcnt(0)" ::: "memory");
    }
    __builtin_amdgcn_s_barrier();
    __builtin_amdgcn_sched_barrier(0);
    #pragma unroll
    for (int ks = 0; ks < 2; ks++) {
      int kc = ks * 4 + quad;
      half8 a[4], b[4];
      #pragma unroll
      for (int tt = 0; tt < 4; tt++) {
        a[tt] = frag_ld(Ah[cur], mw * 64 + tt * 16 + l15, kc);
        b[tt] = frag_ld(Bh[cur], nw * 64 + tt * 16 + l15, kc);
      }
      #pragma unroll
      for (int i = 0; i < 4; i++)
        #pragma unroll
        for (int j = 0; j < 4; j++) acc[i][j] = MF(a[i], b[j], acc[i][j]);
    }
  }
  #pragma unroll
  for (int i = 0; i < 4; i++)
    #pragma unroll
    for (int j = 0; j < 4; j++)
      #pragma unroll
      for (int rg = 0; rg < 4; rg++) {
        int gm = m0 + mw * 64 + i * 16 + quad * 4 + rg;   // d
        int gn = n0 + nw * 64 + j * 16 + l15;             // s
        Vt[(size_t)gm * NR + gn] = (f16)acc[i][j][rg];
      }
}

// ---------------- K4: fused S = Sq X^T / sqrt(D) + row softmax -> P fp16 -------------
// 256 threads (4 waves), block = 32 q x 1024 k x 1 batch. Wave = one 256-key quarter
// of the same 32 rows (acc 128 f32/lane, same as before). 73 KB LDS + 240 regs/wave
// -> 2 independent blocks/CU (two barrier domains fill each other's bubbles; the
// register cap of 8 waves/CU is unchanged but no longer one lockstep group).
// 8 sub-phases per k0 (32-key slices), B ping-pong, counted vmcnt(8)/(10);
// A prefetched one k0 ahead at r==7, hoisted to regs at r==0.
__global__ __launch_bounds__(256, 2) void k_qk(
    const f16* __restrict__ Sqhi, const f16* __restrict__ Sqlo,
    const f16* __restrict__ Xhi, const f16* __restrict__ Xlo,
    f16* __restrict__ Pws, f16* __restrict__ Pd)
{
  __shared__ __align__(16) char Ah[4096], Al[4096];
  __shared__ __align__(16) char Bh[2][16384], Bl[2][16384];   // [buf][qd*4096 + ...]
  __shared__ float redm[4][32], reds[4][32];
  int tid = threadIdx.x, ln = tid & 63;
  int qd = tid >> 6;                    // wave id = key-quarter
  // swizzle decode: z on XCD (L&7); 4 groups of 8 batches; 32 m-tiles per batch
  int L = blockIdx.x;
  int g  = L >> 8;                      // 0..3
  int rr = L & 255;
  int z  = g * 8 + (rr & 7);
  int m0 = (rr >> 3) * 32;
  size_t zr = (size_t)z * SS;
  size_t kb = zr + (size_t)qd * 256;    // this wave's key base
  f32x4 acc[2][16];
  #pragma unroll
  for (int i = 0; i < 2; i++)
    #pragma unroll
    for (int j = 0; j < 16; j++) acc[i][j] = (f32x4)(0.0f);
  int quad = ln >> 4, l15 = ln & 15;

  // prologue: A(k0=0) 2 loads/lane, then B(k0=0,r=0) 8 loads/lane -> 10 in flight
  stageA32(Sqhi, zr + m0, 0, Ah);
  stageA32(Sqlo, zr + m0, 0, Al);
  stageB32w(Xhi, kb, 0, Bh[0] + qd * 4096);
  stageB32w(Xlo, kb, 0, Bl[0] + qd * 4096);

  half8 afh[2][2], afl[2][2];   // A-fragments for the current k0, reused across r
  for (int k0 = 0; k0 < DD; k0 += 64) {
    #pragma unroll
    for (int r = 0; r < 8; r++) {
      // barrier1: all waves done reading buf[(r+1)&1] before overwrite
      __builtin_amdgcn_s_barrier();
      __builtin_amdgcn_sched_barrier(0);
      bool lastPhase = (k0 == DD - 64 && r == 7);
      if (!lastPhase) {
        int nk0 = (r == 7) ? k0 + 64 : k0;
        int nr  = (r + 1) & 7;
        stageB32w(Xhi, kb + nr * 32, nk0, Bh[(r + 1) & 1] + qd * 4096);
        stageB32w(Xlo, kb + nr * 32, nk0, Bl[(r + 1) & 1] + qd * 4096);
        if (r == 7) {
          // prefetch A for next k0 (single buffer: only reader is next r==0 hoist)
          stageA32(Sqhi, zr + m0, k0 + 64, Ah);
          stageA32(Sqlo, zr + m0, k0 + 64, Al);
          asm volatile("s_waitcnt vmcnt(10)" ::: "memory");
        } else {
          asm volatile("s_waitcnt vmcnt(8)" ::: "memory");
        }
      } else {
        asm volatile("s_waitcnt vmcnt(0)" ::: "memory");
      }
      __builtin_amdgcn_s_barrier();
      __builtin_amdgcn_sched_barrier(0);
      if (r == 0) {   // hoist A-fragments: 8 ds_reads per k0
        #pragma unroll
        for (int ks = 0; ks < 2; ks++)
          #pragma unroll
          for (int i = 0; i < 2; i++) {
            afh[ks][i] = frag_ld(Ah, i * 16 + l15, ks * 4 + quad);
            afl[ks][i] = frag_ld(Al, i * 16 + l15, ks * 4 + quad);
          }
      }
      const char* Bhc = Bh[r & 1] + qd * 4096;
      const char* Blc = Bl[r & 1] + qd * 4096;
      #pragma unroll
      for (int ks = 0; ks < 2; ks++) {
        int kc = ks * 4 + quad;
        #pragma unroll
        for (int jj = 0; jj < 2; jj++) {
          half8 bh = frag_ld(Bhc, jj * 16 + l15, kc);
          half8 bl = frag_ld(Blc, jj * 16 + l15, kc);
          #pragma unroll
          for (int i = 0; i < 2; i++) {
            acc[i][r * 2 + jj] = MF(afh[ks][i], bh, acc[i][r * 2 + jj]);
            acc[i][r * 2 + jj] = MF(afh[ks][i], bl, acc[i][r * 2 + jj]);
            acc[i][r * 2 + jj] = MF(afl[ks][i], bh, acc[i][r * 2 + jj]);
          }
        }
      }
    }
  }

  // ---- fused softmax over the full 1024-key row (32 rows per block) ----
  const float scale = 0.044194173824159216f;   // 1/sqrt(512)
  float mx[2][4];
  #pragma unroll
  for (int i = 0; i < 2; i++)
    #pragma unroll
    for (int rg = 0; rg < 4; rg++) mx[i][rg] = -3.0e38f;
  #pragma unroll
  for (int i = 0; i < 2; i++)
    #pragma unroll
    for (int j = 0; j < 16; j++)
      #pragma unroll
      for (int rg = 0; rg < 4; rg++) {
        acc[i][j][rg] *= scale;
        mx[i][rg] = fmaxf(mx[i][rg], acc[i][j][rg]);
      }
  #pragma unroll
  for (int off = 1; off < 16; off <<= 1)
    #pragma unroll
    for (int i = 0; i < 2; i++)
      #pragma unroll
      for (int rg = 0; rg < 4; rg++)
        mx[i][rg] = fmaxf(mx[i][rg], __shfl_xor(mx[i][rg], off, 64));
  if (l15 == 0) {
    #pragma unroll
    for (int i = 0; i < 2; i++)
      #pragma unroll
      for (int rg = 0; rg < 4; rg++)
        redm[qd][i * 16 + quad * 4 + rg] = mx[i][rg];
  }
  __syncthreads();
  float fm[2][4], sum[2][4];
  #pragma unroll
  for (int i = 0; i < 2; i++)
    #pragma unroll
    for (int rg = 0; rg < 4; rg++) {
      int row = i * 16 + quad * 4 + rg;
      fm[i][rg] = fmaxf(fmaxf(redm[0][row], redm[1][row]),
                        fmaxf(redm[2][row], redm[3][row]));
      sum[i][rg] = 0.0f;
    }
  #pragma unroll
  for (int i = 0; i < 2; i++)
    #pragma unroll
    for (int j = 0; j < 16; j++)
      #pragma unroll
      for (int rg = 0; rg < 4; rg++) {
        float e = __expf(acc[i][j][rg] - fm[i][rg]);
        acc[i][j][rg] = e;
        sum[i][rg] += e;
      }
  #pragma unroll
  for (int off = 1; off < 16; off <<= 1)
    #pragma unroll
    for (int i = 0; i < 2; i++)
      #pragma unroll
      for (int rg = 0; rg < 4; rg++)
        sum[i][rg] += __shfl_xor(sum[i][rg], off, 64);
  if (l15 == 0) {
    #pragma unroll
    for (int i = 0; i < 2; i++)
      #pragma unroll
      for (int rg = 0; rg < 4; rg++)
        reds[qd][i * 16 + quad * 4 + rg] = sum[i][rg];
  }
  __syncthreads();
  float inv[2][4];
  #pragma unroll
  for (int i = 0; i < 2; i++)
    #pragma unroll
    for (int rg = 0; rg < 4; rg++) {
      int row = i * 16 + quad * 4 + rg;
      inv[i][rg] = 1.0f / (reds[0][row] + reds[1][row] + reds[2][row] + reds[3][row]);
    }
  f16* Pb = (z < CH) ? Pws : Pd;
  size_t zo = (size_t)((z < CH) ? z : z - CH);
  #pragma unroll
  for (int i = 0; i < 2; i++)
    #pragma unroll
    for (int j = 0; j < 16; j++)
      #pragma unroll
      for (int rg = 0; rg < 4; rg++) {
        int row = i * 16 + quad * 4 + rg;
        int col = qd * 256 + j * 16 + l15;
        Pb[(zo * SS + m0 + row) * SS + col] = (f16)(acc[i][j][rg] * inv[i][rg]);
      }
}

// ---------------- K6: O = P V  (fp16 MFMA), ping-pong pipelined, XCD swizzle --------
__global__ __launch_bounds__(256, 2) void k_pv(
    const f16* __restrict__ P, const f16* __restrict__ Vt, float* __restrict__ O,
    int zoff)
{
  __shared__ __align__(16) char Ah[2][16384], Bh[2][16384];
  int tid = threadIdx.x, wv = tid >> 6, ln = tid & 63;
  int mw = wv & 1, nw = wv >> 1;
  // XCD-bijective swizzle (nwg=512): XCD c owns batches {2c, 2c+1}
  int orig = blockIdx.x;
  int L = (orig & 7) * 64 + (orig >> 3);
  int c = L >> 6, t = L & 63;
  int zl = 2 * c + (t >> 5);          // 0..15
  int m0 = ((t >> 2) & 7) * 128;      // query (within batch)
  int n0 = (t & 3) * 128;             // d_out
  int b  = zoff + zl;                 // global batch
  const char* Pt = (const char*)(P + ((size_t)zl * SS + m0) * SS);
  const char* Vb = (const char*)(Vt + (size_t)n0 * NR + (size_t)b * SS);
  f32x4 acc[4][4];
  #pragma unroll
  for (int i = 0; i < 4; i++)
    #pragma unroll
    for (int j = 0; j < 4; j++) acc[i][j] = (f32x4)(0.0f);
  int quad = ln >> 4, l15 = ln & 15;
  // prologue
  stage128(Pt, 2048, Ah[0], wv, ln);
  stage128(Vb, NR * 2, Bh[0], wv, ln);
  for (int k0 = 0; k0 < SS; k0 += 64) {
    int cur = (k0 >> 6) & 1;
    __builtin_amdgcn_s_barrier();
    __builtin_amdgcn_sched_barrier(0);
    if (k0 + 64 < SS) {
      stage128(Pt + (k0 + 64) * 2, 2048, Ah[cur ^ 1], wv, ln);
      stage128(Vb + (k0 + 64) * 2, NR * 2, Bh[cur ^ 1], wv, ln);
      asm volatile("s_waitcnt vmcnt(8)" ::: "memory");
    } else {
      asm volatile("s_waitcnt vmcnt(0)" ::: "memory");
    }
    __builtin_amdgcn_s_barrier();
    __builtin_amdgcn_sched_barrier(0);
    #pragma unroll
    for (int ks = 0; ks < 2; ks++) {
      int kc = ks * 4 + quad;
      half8 a[4], bf[4];
      #pragma unroll
      for (int tt = 0; tt < 4; tt++) {
        a[tt]  = frag_ld(Ah[cur], mw * 64 + tt * 16 + l15, kc);
        bf[tt] = frag_ld(Bh[cur], nw * 64 + tt * 16 + l15, kc);
      }
      #pragma unroll
      for (int i = 0; i < 4; i++)
        #pragma unroll
        for (int j = 0; j < 4; j++) acc[i][j] = MF(a[i], bf[j], acc[i][j]);
    }
  }
  #pragma unroll
  for (int i = 0; i < 4; i++)
    #pragma unroll
    for (int j = 0; j < 4; j++)
      #pragma unroll
      for (int rg = 0; rg < 4; rg++) {
        int gm = m0 + mw * 64 + i * 16 + quad * 4 + rg;
        int gn = n0 + nw * 64 + j * 16 + l15;
        O[((size_t)b * SS + gm) * DD + gn] = acc[i][j][rg];
      }
}

extern "C" void kernel_launch(void* const* d_in, const int* in_sizes, int n_in,
                              void* d_out, int out_size, void* d_ws, size_t ws_size,
                              hipStream_t stream) {
  const int*   inp   = (const int*)d_in[0];
  const float* wemb  = (const float*)d_in[1];
  const float* pemb  = (const float*)d_in[2];
  const float* gamma = (const float*)d_in[3];
  const float* beta  = (const float*)d_in[4];
  const float* Wk    = (const float*)d_in[5];
  const float* Wq    = (const float*)d_in[6];
  const float* Wv    = (const float*)d_in[7];

  // ws (192 MiB): [Xhi 32M][Xlo 32M][Sqhi 32M][Sqlo 32M][Vt 32M][Pws 32M]
  // P batches 0..15 -> Pws; batches 16..31 -> d_out[0,32M).
  // k_pv runs b=16..31 first (reads d_out[0,32M), writes d_out[32,64M)),
  // then b=0..15 (reads Pws, writes d_out[0,32M)). Stream order makes this safe.
  char* ws = (char*)d_ws;
  f16* Xhi  = (f16*)ws;
  f16* Xlo  = (f16*)(ws + ((size_t)32 << 20));
  f16* Sqhi = (f16*)(ws + ((size_t)64 << 20));
  f16* Sqlo = (f16*)(ws + ((size_t)96 << 20));
  f16* Vt   = (f16*)(ws + ((size_t)128 << 20));
  f16* Pws  = (f16*)(ws + ((size_t)160 << 20));
  f16* Pd   = (f16*)d_out;

  f16* Wqh  = (f16*)d_out;
  f16* Wql  = Wqh + (size_t)DD * DD;
  f16* Wkh  = Wql + (size_t)DD * DD;
  f16* Wkl  = Wkh + (size_t)DD * DD;
  f16* Wvt  = Wkl + (size_t)DD * DD;
  f16* Mthi = Wvt + (size_t)DD * DD;
  f16* Mtlo = Mthi + (size_t)DD * DD;

  k_prep<<<NR + 192, 256, 0, stream>>>(inp, wemb, pemb, gamma, beta, Xhi, Xlo,
                                       Wq, Wk, Wv, Wqh, Wql, Wkh, Wkl, Wvt);
  k_mt<<<dim3(DD / 128, DD / 128), 256, 0, stream>>>(Wkh, Wkl, Wqh, Wql, Mthi, Mtlo);
  k_projm<<<1024, 512, 0, stream>>>(Xhi, Xlo, Mthi, Mtlo, Sqhi, Sqlo);
  k_vt<<<1024, 256, 0, stream>>>(Wvt, Xhi, Vt);
  k_qk<<<1024, 256, 0, stream>>>(Sqhi, Sqlo, Xhi, Xlo, Pws, Pd);
  k_pv<<<512, 256, 0, stream>>>(Pd,  Vt, (float*)d_out, CH);
  k_pv<<<512, 256, 0, stream>>>(Pws, Vt, (float*)d_out, 0);
}

// Round 12
// 393.097 us; speedup vs baseline: 1.7227x; 1.0588x over previous
//
#include <hip/hip_runtime.h>
#include <math.h>

typedef _Float16 f16;
typedef _Float16 half8 __attribute__((ext_vector_type(8)));
typedef _Float16 hv2 __attribute__((ext_vector_type(2)));
typedef _Float16 hv4 __attribute__((ext_vector_type(4)));
typedef float f32x4 __attribute__((ext_vector_type(4)));
typedef __attribute__((address_space(1))) const unsigned int gu32;
typedef __attribute__((address_space(3))) unsigned int lu32;

#define BB 32
#define SS 1024
#define DD 512
#define NR (BB*SS)   // 32768
#define CH 16

// ---------- m97-style staging helpers (128B rows, 16B chunks, xor-swizzle row&7) ----------
__device__ __forceinline__ void stage128(const char* g, int ldb, char* lds,
                                         int wv, int ln) {
  #pragma unroll
  for (int r = 0; r < 4; r++) {
    int slot = r * 256 + wv * 64 + ln;
    int row = slot >> 3, cp = slot & 7;
    int c = cp ^ (row & 7);
    const char* gp = g + (size_t)row * ldb + (c << 4);
    char* lp = lds + ((slot - ln) << 4);
    __builtin_amdgcn_global_load_lds((gu32*)gp, (lu32*)lp, 16, 0, 0);
  }
}

// 64 rows x 128B (8KB) staged by 512 threads, one 16B slot each
__device__ __forceinline__ void stage8k_512(const char* g, int ldb, char* lds) {
  int tid = threadIdx.x;
  int slot = tid;
  int row = slot >> 3, cp = slot & 7;
  int c = cp ^ (row & 7);
  const char* gp = g + (size_t)row * ldb + (c << 4);
  char* lp = lds + ((slot - (tid & 63)) << 4);
  __builtin_amdgcn_global_load_lds((gu32*)gp, (lu32*)lp, 16, 0, 0);
}

__device__ __forceinline__ half8 frag_ld(const char* lds, int row, int kc) {
  return *(const half8*)(lds + row * 128 + ((kc ^ (row & 7)) << 4));
}

__device__ __forceinline__ f32x4 MF(half8 a, half8 b, f32x4 c) {
  return __builtin_amdgcn_mfma_f32_16x16x32_f16(a, b, c, 0, 0, 0);
}

// ---------------- K1: merged embedding+LN; weight split (Wq/Wk plain, Wv transposed) -----
__global__ __launch_bounds__(256) void k_prep(
    const int* __restrict__ inp, const float* __restrict__ wemb,
    const float* __restrict__ pemb, const float* __restrict__ gamma,
    const float* __restrict__ beta, f16* __restrict__ Xhi, f16* __restrict__ Xlo,
    const float* __restrict__ Wq, const float* __restrict__ Wk,
    const float* __restrict__ Wv, f16* __restrict__ Wqh, f16* __restrict__ Wql,
    f16* __restrict__ Wkh, f16* __restrict__ Wkl, f16* __restrict__ Wvt)
{
  int bid = blockIdx.x;
  int tid = threadIdx.x;
  __shared__ float red[10];
  __shared__ float Lt[64][65];
  if (bid >= NR) {
    int t  = bid - NR;           // 0..191
    int mz = t >> 6;             // 0=Wq 1=Wk 2=Wv
    int tt = t & 63;
    if (mz < 2) {                // ---- Wq/Wk: plain hi/lo split, keep [d][h] layout ----
      const float* W = mz ? Wk : Wq;
      f16* Oh = mz ? Wkh : Wqh;
      f16* Ol = mz ? Wkl : Wql;
      #pragma unroll
      for (int p = 0; p < 4; p++) {
        size_t base = (size_t)tt * 4096 + p * 1024 + tid * 4;
        float4 v = *(const float4*)&W[base];
        f16 h0 = (f16)v.x, h1 = (f16)v.y, h2 = (f16)v.z, h3 = (f16)v.w;
        hv4 hi = {h0, h1, h2, h3};
        hv4 lo = {(f16)(v.x - (float)h0), (f16)(v.y - (float)h1),
                  (f16)(v.z - (float)h2), (f16)(v.w - (float)h3)};
        *(hv4*)&Oh[base] = hi;
        *(hv4*)&Ol[base] = lo;
      }
      return;
    }
    // ---- Wv: 64x64 LDS-tiled transpose -> Wvt[h][d] ----
    int tr = tt >> 3, tc = tt & 7;
    int rr = tid >> 4;           // 0..15
    int c4 = (tid & 15) * 4;
    #pragma unroll
    for (int p = 0; p < 4; p++) {
      float4 v = *(const float4*)&Wv[(size_t)(tr * 64 + p * 16 + rr) * DD + tc * 64 + c4];
      Lt[p * 16 + rr][c4 + 0] = v.x; Lt[p * 16 + rr][c4 + 1] = v.y;
      Lt[p * 16 + rr][c4 + 2] = v.z; Lt[p * 16 + rr][c4 + 3] = v.w;
    }
    __syncthreads();
    #pragma unroll
    for (int p = 0; p < 4; p++) {
      int dl = p * 16 + rr;
      float v0 = Lt[c4 + 0][dl], v1 = Lt[c4 + 1][dl];
      float v2 = Lt[c4 + 2][dl], v3 = Lt[c4 + 3][dl];
      size_t o = (size_t)(tc * 64 + dl) * DD + tr * 64 + c4;
      *(hv4*)&Wvt[o] = (hv4){(f16)v0, (f16)v1, (f16)v2, (f16)v3};
    }
    return;
  }
  // ---- embedding + layernorm -> split fp16 X ----
  int row = bid;
  int s   = row & (SS - 1);
  int tok = inp[row];
  float2 w = ((const float2*)(wemb + (size_t)tok * DD))[tid];
  float2 p = ((const float2*)(pemb + (size_t)s   * DD))[tid];
  float ex = w.x + p.x, ey = w.y + p.y;
  float sum = ex + ey, ssq = ex*ex + ey*ey;
  #pragma unroll
  for (int off = 32; off > 0; off >>= 1) {
    sum += __shfl_down(sum, off, 64);
    ssq += __shfl_down(ssq, off, 64);
  }
  int wv = tid >> 6, ln = tid & 63;
  if (ln == 0) { red[wv] = sum; red[4 + wv] = ssq; }
  __syncthreads();
  if (tid == 0) {
    float s4 = red[0] + red[1] + red[2] + red[3];
    float q4 = red[4] + red[5] + red[6] + red[7];
    float mean = s4 * (1.0f / DD);
    float var  = q4 * (1.0f / DD) - mean * mean;
    red[8] = mean; red[9] = rsqrtf(var + 1e-5f);
  }
  __syncthreads();
  float mean = red[8], rstd = red[9];
  float2 g  = ((const float2*)gamma)[tid];
  float2 bt = ((const float2*)beta)[tid];
  float ox = (ex - mean) * rstd * g.x + bt.x;
  float oy = (ey - mean) * rstd * g.y + bt.y;
  f16 hx = (f16)ox, hy = (f16)oy;
  f16 lx = (f16)(ox - (float)hx), ly = (f16)(oy - (float)hy);
  ((hv2*)(Xhi + (size_t)row * DD))[tid] = (hv2){hx, hy};
  ((hv2*)(Xlo + (size_t)row * DD))[tid] = (hv2){lx, ly};
}

// ---------------- K2a: Mt[e][d] = sum_h Wk[e][h] Wq[d][h] (3-term split) -----
__global__ __launch_bounds__(256, 2) void k_mt(
    const f16* __restrict__ Wkh, const f16* __restrict__ Wkl,
    const f16* __restrict__ Wqh, const f16* __restrict__ Wql,
    f16* __restrict__ Mthi, f16* __restrict__ Mtlo)
{
  __shared__ __align__(16) char Ah[16384], Al[16384], Bh[16384], Bl[16384];
  int tid = threadIdx.x, wv = tid >> 6, ln = tid & 63;
  int mw = wv & 1, nw = wv >> 1;
  int n0 = blockIdx.x * 128;   // d
  int m0 = blockIdx.y * 128;   // e
  f32x4 acc[4][4];
  #pragma unroll
  for (int i = 0; i < 4; i++)
    #pragma unroll
    for (int j = 0; j < 4; j++) acc[i][j] = (f32x4)(0.0f);
  int quad = ln >> 4, l15 = ln & 15;
  for (int k0 = 0; k0 < DD; k0 += 64) {
    __syncthreads();
    stage128((const char*)(Wkh + (size_t)m0 * DD + k0), 1024, Ah, wv, ln);
    stage128((const char*)(Wkl + (size_t)m0 * DD + k0), 1024, Al, wv, ln);
    stage128((const char*)(Wqh + (size_t)n0 * DD + k0), 1024, Bh, wv, ln);
    stage128((const char*)(Wql + (size_t)n0 * DD + k0), 1024, Bl, wv, ln);
    __syncthreads();
    #pragma unroll
    for (int ks = 0; ks < 2; ks++) {
      int kc = ks * 4 + quad;
      half8 ah[4], al[4], bh[4], bl[4];
      #pragma unroll
      for (int t = 0; t < 4; t++) {
        ah[t] = frag_ld(Ah, mw * 64 + t * 16 + l15, kc);
        al[t] = frag_ld(Al, mw * 64 + t * 16 + l15, kc);
        bh[t] = frag_ld(Bh, nw * 64 + t * 16 + l15, kc);
        bl[t] = frag_ld(Bl, nw * 64 + t * 16 + l15, kc);
      }
      #pragma unroll
      for (int i = 0; i < 4; i++)
        #pragma unroll
        for (int j = 0; j < 4; j++) {
          acc[i][j] = MF(ah[i], bh[j], acc[i][j]);
          acc[i][j] = MF(ah[i], bl[j], acc[i][j]);
          acc[i][j] = MF(al[i], bh[j], acc[i][j]);
        }
    }
  }
  #pragma unroll
  for (int i = 0; i < 4; i++)
    #pragma unroll
    for (int j = 0; j < 4; j++)
      #pragma unroll
      for (int rg = 0; rg < 4; rg++) {
        int gm = m0 + mw * 64 + i * 16 + quad * 4 + rg;   // e
        int gn = n0 + nw * 64 + j * 16 + l15;             // d
        size_t o = (size_t)gm * DD + gn;
        float v = acc[i][j][rg];
        f16 h = (f16)v;
        Mthi[o] = h; Mtlo[o] = (f16)(v - (float)h);
      }
}

// ---------------- K2b+K3 merged: blocks [0,1024) = Sq = X*Mt^T (3-term, 128x128);
//                  blocks [1024,2048) = Vt[d][s] ping-pong GEMM. 64KB LDS both ----
__global__ __launch_bounds__(256, 2) void k_pjvt(
    const f16* __restrict__ Xhi, const f16* __restrict__ Xlo,
    const f16* __restrict__ Mthi, const f16* __restrict__ Mtlo,
    f16* __restrict__ Sqhi, f16* __restrict__ Sqlo,
    const f16* __restrict__ Wvt, f16* __restrict__ Vt)
{
  __shared__ __align__(16) char Lds[65536];
  int bid = blockIdx.x;
  int tid = threadIdx.x, wv = tid >> 6, ln = tid & 63;
  int quad = ln >> 4, l15 = ln & 15;
  if (bid < 1024) {
    // ---- projm branch (round-1 verified body + XCD swizzle) ----
    char* Ah = Lds;           char* Al = Lds + 16384;
    char* Bh = Lds + 32768;   char* Bl = Lds + 49152;
    int mw = wv & 1, nw = wv >> 1;
    // swizzle: the 4 same-m0 blocks (xb=0..3) share an XCD
    int L = bid;
    int xb = (L >> 3) & 3;
    int y  = ((L >> 5) << 3) + (L & 7);
    int n0 = xb * 128;  // e
    int m0 = y * 128;   // s
    f32x4 acc[4][4];
    #pragma unroll
    for (int i = 0; i < 4; i++)
      #pragma unroll
      for (int j = 0; j < 4; j++) acc[i][j] = (f32x4)(0.0f);
    for (int k0 = 0; k0 < DD; k0 += 64) {
      __syncthreads();
      stage128((const char*)(Xhi  + (size_t)m0 * DD + k0), 1024, Ah, wv, ln);
      stage128((const char*)(Xlo  + (size_t)m0 * DD + k0), 1024, Al, wv, ln);
      stage128((const char*)(Mthi + (size_t)n0 * DD + k0), 1024, Bh, wv, ln);
      stage128((const char*)(Mtlo + (size_t)n0 * DD + k0), 1024, Bl, wv, ln);
      __syncthreads();
      #pragma unroll
      for (int ks = 0; ks < 2; ks++) {
        int kc = ks * 4 + quad;
        half8 ah[4], al[4], bh[4], bl[4];
        #pragma unroll
        for (int t = 0; t < 4; t++) {
          ah[t] = frag_ld(Ah, mw * 64 + t * 16 + l15, kc);
          al[t] = frag_ld(Al, mw * 64 + t * 16 + l15, kc);
          bh[t] = frag_ld(Bh, nw * 64 + t * 16 + l15, kc);
          bl[t] = frag_ld(Bl, nw * 64 + t * 16 + l15, kc);
        }
        #pragma unroll
        for (int i = 0; i < 4; i++)
          #pragma unroll
          for (int j = 0; j < 4; j++) {
            acc[i][j] = MF(ah[i], bh[j], acc[i][j]);
            acc[i][j] = MF(ah[i], bl[j], acc[i][j]);
            acc[i][j] = MF(al[i], bh[j], acc[i][j]);
          }
      }
    }
    #pragma unroll
    for (int i = 0; i < 4; i++)
      #pragma unroll
      for (int j = 0; j < 4; j++)
        #pragma unroll
        for (int rg = 0; rg < 4; rg++) {
          int gm = m0 + mw * 64 + i * 16 + quad * 4 + rg;
          int gn = n0 + nw * 64 + j * 16 + l15;
          size_t o = (size_t)gm * DD + gn;
          float v = acc[i][j][rg];
          f16 h = (f16)v;
          Sqhi[o] = h; Sqlo[o] = (f16)(v - (float)h);
        }
  } else {
    // ---- vt branch (verified body; orig in [0,1024), same XCD mapping) ----
    int mw = wv & 1, nw = wv >> 1;
    int orig = bid - 1024;
    int L = (orig & 7) * 128 + (orig >> 3);
    int c = L >> 7, t = L & 127;
    int m0 = (t & 3) * 128;                // d
    int n0 = (c * 32 + (t >> 2)) * 128;    // s
    f32x4 acc[4][4];
    #pragma unroll
    for (int i = 0; i < 4; i++)
      #pragma unroll
      for (int j = 0; j < 4; j++) acc[i][j] = (f32x4)(0.0f);
    // prologue into buf 0
    stage128((const char*)(Wvt + (size_t)m0 * DD), 1024, Lds, wv, ln);
    stage128((const char*)(Xhi + (size_t)n0 * DD), 1024, Lds + 32768, wv, ln);
    for (int k0 = 0; k0 < DD; k0 += 64) {
      int cur = (k0 >> 6) & 1;
      char* Ac = Lds + cur * 16384;
      char* Bc = Lds + 32768 + cur * 16384;
      __builtin_amdgcn_s_barrier();
      __builtin_amdgcn_sched_barrier(0);
      if (k0 + 64 < DD) {
        stage128((const char*)(Wvt + (size_t)m0 * DD + k0 + 64), 1024,
                 Lds + (cur ^ 1) * 16384, wv, ln);
        stage128((const char*)(Xhi + (size_t)n0 * DD + k0 + 64), 1024,
                 Lds + 32768 + (cur ^ 1) * 16384, wv, ln);
        asm volatile("s_waitcnt vmcnt(8)" ::: "memory");
      } else {
        asm volatile("s_waitcnt vmcnt(0)" ::: "memory");
      }
      __builtin_amdgcn_s_barrier();
      __builtin_amdgcn_sched_barrier(0);
      #pragma unroll
      for (int ks = 0; ks < 2; ks++) {
        int kc = ks * 4 + quad;
        half8 a[4], b[4];
        #pragma unroll
        for (int tt = 0; tt < 4; tt++) {
          a[tt] = frag_ld(Ac, mw * 64 + tt * 16 + l15, kc);
          b[tt] = frag_ld(Bc, nw * 64 + tt * 16 + l15, kc);
        }
        #pragma unroll
        for (int i = 0; i < 4; i++)
          #pragma unroll
          for (int j = 0; j < 4; j++) acc[i][j] = MF(a[i], b[j], acc[i][j]);
      }
    }
    #pragma unroll
    for (int i = 0; i < 4; i++)
      #pragma unroll
      for (int j = 0; j < 4; j++)
        #pragma unroll
        for (int rg = 0; rg < 4; rg++) {
          int gm = m0 + mw * 64 + i * 16 + quad * 4 + rg;   // d
          int gn = n0 + nw * 64 + j * 16 + l15;             // s
          Vt[(size_t)gm * NR + gn] = (f16)acc[i][j][rg];
        }
  }
}

// ---------------- K4: fused S = Sq X^T / sqrt(D) + row softmax -> P fp16 -------------
// ROUND-7 VERIFIED STRUCTURE (121.4 us): 512 threads, 64 q x 1024 k x 1 batch.
// B ping-pong (4x 8KB slices) + counted vmcnt(8); A staged to LDS, prefetched one
// k0 AHEAD at r==3 (vmcnt(10) there), hoisted to regs at r==0. No setprio.
__global__ __launch_bounds__(512, 2) void k_qk(
    const f16* __restrict__ Sqhi, const f16* __restrict__ Sqlo,
    const f16* __restrict__ Xhi, const f16* __restrict__ Xlo,
    f16* __restrict__ Pws, f16* __restrict__ Pd)
{
  __shared__ __align__(16) char Ah[8192], Al[8192];
  __shared__ __align__(16) char Bh[2][4][8192], Bl[2][4][8192];
  __shared__ float redm[4][64], reds[4][64];
  int tid = threadIdx.x, wv = tid >> 6, ln = tid & 63;
  int rowg = wv & 1, qd = wv >> 1;
  // swizzle decode: L = g*128 + j*8 + xcd;  z = g*8 + xcd, m0 = j*64
  int L = blockIdx.x;
  int g  = L >> 7;
  int rr = L & 127;
  int z  = g * 8 + (rr & 7);
  int m0 = (rr >> 3) * 64;
  size_t zr = (size_t)z * SS;
  f32x4 acc[2][16];
  #pragma unroll
  for (int i = 0; i < 2; i++)
    #pragma unroll
    for (int j = 0; j < 16; j++) acc[i][j] = (f32x4)(0.0f);
  int quad = ln >> 4, l15 = ln & 15;

  // prologue: A(k0=0) then B(k0=0, r=0) into buf 0 -> queue = [A2, B8]
  stage8k_512((const char*)(Sqhi + (zr + m0) * DD), 1024, Ah);
  stage8k_512((const char*)(Sqlo + (zr + m0) * DD), 1024, Al);
  #pragma unroll
  for (int q4 = 0; q4 < 4; q4++) {
    stage8k_512((const char*)(Xhi + (zr + q4 * 256) * DD), 1024, Bh[0][q4]);
    stage8k_512((const char*)(Xlo + (zr + q4 * 256) * DD), 1024, Bl[0][q4]);
  }

  half8 afh[2][2], afl[2][2];   // A-fragments for the current k0, reused across r
  for (int k0 = 0; k0 < DD; k0 += 64) {
    #pragma unroll
    for (int r = 0; r < 4; r++) {
      // barrier1: all waves done reading buf[(r+1)&1] (from phase p-1) before overwrite
      __builtin_amdgcn_s_barrier();
      __builtin_amdgcn_sched_barrier(0);
      bool lastPhase = (k0 == DD - 64 && r == 3);
      if (!lastPhase) {
        int nk0 = (r == 3) ? k0 + 64 : k0;
        int nr  = (r + 1) & 3;
        #pragma unroll
        for (int q4 = 0; q4 < 4; q4++) {
          int n0 = q4 * 256 + nr * 64;
          stage8k_512((const char*)(Xhi + (zr + n0) * DD + nk0), 1024, Bh[(r + 1) & 1][q4]);
          stage8k_512((const char*)(Xlo + (zr + n0) * DD + nk0), 1024, Bl[(r + 1) & 1][q4]);
        }
        if (r == 3) {
          // prefetch A for next k0 (single buffer: only reader is next r==0 hoist)
          stage8k_512((const char*)(Sqhi + (zr + m0) * DD + k0 + 64), 1024, Ah);
          stage8k_512((const char*)(Sqlo + (zr + m0) * DD + k0 + 64), 1024, Al);
          asm volatile("s_waitcnt vmcnt(10)" ::: "memory");
        } else {
          asm volatile("s_waitcnt vmcnt(8)" ::: "memory");
        }
      } else {
        asm volatile("s_waitcnt vmcnt(0)" ::: "memory");
      }
      __builtin_amdgcn_s_barrier();
      __builtin_amdgcn_sched_barrier(0);
      if (r == 0) {   // hoist A-fragments: 8 ds_reads per k0
        #pragma unroll
        for (int ks = 0; ks < 2; ks++)
          #pragma unroll
          for (int i = 0; i < 2; i++) {
            afh[ks][i] = frag_ld(Ah, rowg * 32 + i * 16 + l15, ks * 4 + quad);
            afl[ks][i] = frag_ld(Al, rowg * 32 + i * 16 + l15, ks * 4 + quad);
          }
      }
      #pragma unroll
      for (int ks = 0; ks < 2; ks++) {
        int kc = ks * 4 + quad;
        #pragma unroll
        for (int jj = 0; jj < 4; jj++) {
          half8 bh = frag_ld(Bh[r & 1][qd], jj * 16 + l15, kc);
          half8 bl = frag_ld(Bl[r & 1][qd], jj * 16 + l15, kc);
          #pragma unroll
          for (int i = 0; i < 2; i++) {
            acc[i][r * 4 + jj] = MF(afh[ks][i], bh, acc[i][r * 4 + jj]);
            acc[i][r * 4 + jj] = MF(afh[ks][i], bl, acc[i][r * 4 + jj]);
            acc[i][r * 4 + jj] = MF(afl[ks][i], bh, acc[i][r * 4 + jj]);
          }
        }
      }
    }
  }

  // ---- fused softmax over the full 1024-key row ----
  const float scale = 0.044194173824159216f;   // 1/sqrt(512)
  float mx[2][4];
  #pragma unroll
  for (int i = 0; i < 2; i++)
    #pragma unroll
    for (int rg = 0; rg < 4; rg++) mx[i][rg] = -3.0e38f;
  #pragma unroll
  for (int i = 0; i < 2; i++)
    #pragma unroll
    for (int j = 0; j < 16; j++)
      #pragma unroll
      for (int rg = 0; rg < 4; rg++) {
        acc[i][j][rg] *= scale;
        mx[i][rg] = fmaxf(mx[i][rg], acc[i][j][rg]);
      }
  #pragma unroll
  for (int off = 1; off < 16; off <<= 1)
    #pragma unroll
    for (int i = 0; i < 2; i++)
      #pragma unroll
      for (int rg = 0; rg < 4; rg++)
        mx[i][rg] = fmaxf(mx[i][rg], __shfl_xor(mx[i][rg], off, 64));
  if (l15 == 0) {
    #pragma unroll
    for (int i = 0; i < 2; i++)
      #pragma unroll
      for (int rg = 0; rg < 4; rg++)
        redm[qd][rowg * 32 + i * 16 + quad * 4 + rg] = mx[i][rg];
  }
  __syncthreads();
  float fm[2][4], sum[2][4];
  #pragma unroll
  for (int i = 0; i < 2; i++)
    #pragma unroll
    for (int rg = 0; rg < 4; rg++) {
      int row = rowg * 32 + i * 16 + quad * 4 + rg;
      fm[i][rg] = fmaxf(fmaxf(redm[0][row], redm[1][row]),
                        fmaxf(redm[2][row], redm[3][row]));
      sum[i][rg] = 0.0f;
    }
  #pragma unroll
  for (int i = 0; i < 2; i++)
    #pragma unroll
    for (int j = 0; j < 16; j++)
      #pragma unroll
      for (int rg = 0; rg < 4; rg++) {
        float e = __expf(acc[i][j][rg] - fm[i][rg]);
        acc[i][j][rg] = e;
        sum[i][rg] += e;
      }
  #pragma unroll
  for (int off = 1; off < 16; off <<= 1)
    #pragma unroll
    for (int i = 0; i < 2; i++)
      #pragma unroll
      for (int rg = 0; rg < 4; rg++)
        sum[i][rg] += __shfl_xor(sum[i][rg], off, 64);
  if (l15 == 0) {
    #pragma unroll
    for (int i = 0; i < 2; i++)
      #pragma unroll
      for (int rg = 0; rg < 4; rg++)
        reds[qd][rowg * 32 + i * 16 + quad * 4 + rg] = sum[i][rg];
  }
  __syncthreads();
  float inv[2][4];
  #pragma unroll
  for (int i = 0; i < 2; i++)
    #pragma unroll
    for (int rg = 0; rg < 4; rg++) {
      int row = rowg * 32 + i * 16 + quad * 4 + rg;
      inv[i][rg] = 1.0f / (reds[0][row] + reds[1][row] + reds[2][row] + reds[3][row]);
    }
  f16* Pb = (z < CH) ? Pws : Pd;
  size_t zo = (size_t)((z < CH) ? z : z - CH);
  #pragma unroll
  for (int i = 0; i < 2; i++)
    #pragma unroll
    for (int j = 0; j < 16; j++)
      #pragma unroll
      for (int rg = 0; rg < 4; rg++) {
        int row = rowg * 32 + i * 16 + quad * 4 + rg;
        int col = qd * 256 + j * 16 + l15;
        Pb[(zo * SS + m0 + row) * SS + col] = (f16)(acc[i][j][rg] * inv[i][rg]);
      }
}

// ---------------- K6: O = P V  (fp16 MFMA), ping-pong pipelined, XCD swizzle --------
__global__ __launch_bounds__(256, 2) void k_pv(
    const f16* __restrict__ P, const f16* __restrict__ Vt, float* __restrict__ O,
    int zoff)
{
  __shared__ __align__(16) char Ah[2][16384], Bh[2][16384];
  int tid = threadIdx.x, wv = tid >> 6, ln = tid & 63;
  int mw = wv & 1, nw = wv >> 1;
  // XCD-bijective swizzle (nwg=512): XCD c owns batches {2c, 2c+1}
  int orig = blockIdx.x;
  int L = (orig & 7) * 64 + (orig >> 3);
  int c = L >> 6, t = L & 63;
  int zl = 2 * c + (t >> 5);          // 0..15
  int m0 = ((t >> 2) & 7) * 128;      // query (within batch)
  int n0 = (t & 3) * 128;             // d_out
  int b  = zoff + zl;                 // global batch
  const char* Pt = (const char*)(P + ((size_t)zl * SS + m0) * SS);
  const char* Vb = (const char*)(Vt + (size_t)n0 * NR + (size_t)b * SS);
  f32x4 acc[4][4];
  #pragma unroll
  for (int i = 0; i < 4; i++)
    #pragma unroll
    for (int j = 0; j < 4; j++) acc[i][j] = (f32x4)(0.0f);
  int quad = ln >> 4, l15 = ln & 15;
  // prologue
  stage128(Pt, 2048, Ah[0], wv, ln);
  stage128(Vb, NR * 2, Bh[0], wv, ln);
  for (int k0 = 0; k0 < SS; k0 += 64) {
    int cur = (k0 >> 6) & 1;
    __builtin_amdgcn_s_barrier();
    __builtin_amdgcn_sched_barrier(0);
    if (k0 + 64 < SS) {
      stage128(Pt + (k0 + 64) * 2, 2048, Ah[cur ^ 1], wv, ln);
      stage128(Vb + (k0 + 64) * 2, NR * 2, Bh[cur ^ 1], wv, ln);
      asm volatile("s_waitcnt vmcnt(8)" ::: "memory");
    } else {
      asm volatile("s_waitcnt vmcnt(0)" ::: "memory");
    }
    __builtin_amdgcn_s_barrier();
    __builtin_amdgcn_sched_barrier(0);
    #pragma unroll
    for (int ks = 0; ks < 2; ks++) {
      int kc = ks * 4 + quad;
      half8 a[4], bf[4];
      #pragma unroll
      for (int tt = 0; tt < 4; tt++) {
        a[tt]  = frag_ld(Ah[cur], mw * 64 + tt * 16 + l15, kc);
        bf[tt] = frag_ld(Bh[cur], nw * 64 + tt * 16 + l15, kc);
      }
      #pragma unroll
      for (int i = 0; i < 4; i++)
        #pragma unroll
        for (int j = 0; j < 4; j++) acc[i][j] = MF(a[i], bf[j], acc[i][j]);
    }
  }
  #pragma unroll
  for (int i = 0; i < 4; i++)
    #pragma unroll
    for (int j = 0; j < 4; j++)
      #pragma unroll
      for (int rg = 0; rg < 4; rg++) {
        int gm = m0 + mw * 64 + i * 16 + quad * 4 + rg;
        int gn = n0 + nw * 64 + j * 16 + l15;
        O[((size_t)b * SS + gm) * DD + gn] = acc[i][j][rg];
      }
}

extern "C" void kernel_launch(void* const* d_in, const int* in_sizes, int n_in,
                              void* d_out, int out_size, void* d_ws, size_t ws_size,
                              hipStream_t stream) {
  const int*   inp   = (const int*)d_in[0];
  const float* wemb  = (const float*)d_in[1];
  const float* pemb  = (const float*)d_in[2];
  const float* gamma = (const float*)d_in[3];
  const float* beta  = (const float*)d_in[4];
  const float* Wk    = (const float*)d_in[5];
  const float* Wq    = (const float*)d_in[6];
  const float* Wv    = (const float*)d_in[7];

  // ws (192 MiB): [Xhi 32M][Xlo 32M][Sqhi 32M][Sqlo 32M][Vt 32M][Pws 32M]
  // P batches 0..15 -> Pws; batches 16..31 -> d_out[0,32M).
  // k_pv runs b=16..31 first (reads d_out[0,32M), writes d_out[32,64M)),
  // then b=0..15 (reads Pws, writes d_out[0,32M)). Stream order makes this safe.
  char* ws = (char*)d_ws;
  f16* Xhi  = (f16*)ws;
  f16* Xlo  = (f16*)(ws + ((size_t)32 << 20));
  f16* Sqhi = (f16*)(ws + ((size_t)64 << 20));
  f16* Sqlo = (f16*)(ws + ((size_t)96 << 20));
  f16* Vt   = (f16*)(ws + ((size_t)128 << 20));
  f16* Pws  = (f16*)(ws + ((size_t)160 << 20));
  f16* Pd   = (f16*)d_out;

  f16* Wqh  = (f16*)d_out;
  f16* Wql  = Wqh + (size_t)DD * DD;
  f16* Wkh  = Wql + (size_t)DD * DD;
  f16* Wkl  = Wkh + (size_t)DD * DD;
  f16* Wvt  = Wkl + (size_t)DD * DD;
  f16* Mthi = Wvt + (size_t)DD * DD;
  f16* Mtlo = Mthi + (size_t)DD * DD;

  k_prep<<<NR + 192, 256, 0, stream>>>(inp, wemb, pemb, gamma, beta, Xhi, Xlo,
                                       Wq, Wk, Wv, Wqh, Wql, Wkh, Wkl, Wvt);
  k_mt<<<dim3(DD / 128, DD / 128), 256, 0, stream>>>(Wkh, Wkl, Wqh, Wql, Mthi, Mtlo);
  k_pjvt<<<2048, 256, 0, stream>>>(Xhi, Xlo, Mthi, Mtlo, Sqhi, Sqlo, Wvt, Vt);
  k_qk<<<512, 512, 0, stream>>>(Sqhi, Sqlo, Xhi, Xlo, Pws, Pd);
  k_pv<<<512, 256, 0, stream>>>(Pd,  Vt, (float*)d_out, CH);
  k_pv<<<512, 256, 0, stream>>>(Pws, Vt, (float*)d_out, 0);
}